// Round 10
// baseline (613.527 us; speedup 1.0000x reference)
//
#include <hip/hip_runtime.h>
#include <hip/hip_bf16.h>

typedef __hip_bfloat16 bf16;
typedef __attribute__((ext_vector_type(8))) short short8v;
typedef __attribute__((ext_vector_type(16))) float f32x16;

__device__ __forceinline__ float tof(float v){ return v; }
__device__ __forceinline__ float tof(bf16 v){ return __bfloat162float(v); }
__device__ __forceinline__ void sto(float* p, float v){ *p = v; }
__device__ __forceinline__ void sto(bf16* p, float v){ *p = __float2bfloat16(v); }
__device__ __forceinline__ short f2bs(float f){ bf16 h = __float2bfloat16(f); return *(short*)&h; }
__device__ __forceinline__ float bsu2f(short s){
    return __uint_as_float(((unsigned)(unsigned short)s) << 16);
}

__device__ __forceinline__ void sto4(float* p, float4 v){ *(float4*)p = v; }
__device__ __forceinline__ void sto4(bf16* p, float4 v){
    short4 s; s.x=f2bs(v.x); s.y=f2bs(v.y); s.z=f2bs(v.z); s.w=f2bs(v.w);
    *(short4*)p = s;
}

// XCD-aware swizzle for 64-frame (t) problems: grid = 64 << bs blocks.
__device__ __forceinline__ void swz_t(int b, int bs, int& t, int& rem){
    int x = b & 7, k = b >> 3;
    t = x*8 + (k >> bs);
    rem = k & ((1 << bs) - 1);
}

// ---------- audio embedding ----------
__global__ __launch_bounds__(64) void k_audio(const float* __restrict__ hs,
    const float* __restrict__ w, const float* __restrict__ b, float* __restrict__ out)
{
    int t = blockIdx.x, l = threadIdx.x;
    float acc = b[l];
    const float* h = hs + t*768;
    #pragma unroll 4
    for (int k = 0; k < 768; k++) acc += h[k] * w[k*64 + l];
    out[t*64 + l] = acc;
}

// ---------- enc_lat ----------
__global__ __launch_bounds__(256) void k_enclat(const float* __restrict__ flat,
    const float* __restrict__ w, const float* __restrict__ b, float* __restrict__ out)
{
    __shared__ float red[256];
    int l = blockIdx.x, tid = threadIdx.x;
    float acc = 0.f;
    for (int k = tid; k < 4096; k += 256) acc += flat[k] * w[k*64 + l];
    red[tid] = acc; __syncthreads();
    for (int s = 128; s > 0; s >>= 1){ if (tid < s) red[tid] += red[tid+s]; __syncthreads(); }
    if (tid == 0) out[l] = red[0] + b[l];
}

// ---------- dec_lin fused with latent concat; bf16 out [t][32][128] ----------
__global__ __launch_bounds__(256) void k_declin4(const float* __restrict__ ae,
    const float* __restrict__ pe, const float* __restrict__ w, const float* __restrict__ b,
    bf16* __restrict__ out)
{
    int n4 = blockIdx.x*256 + threadIdx.x;   // 0..1023
    int t = blockIdx.y;
    float4 acc = *(const float4*)&b[n4*4];
    const float* a = ae + t*64;
    #pragma unroll 4
    for (int k = 0; k < 64; k++){
        float av = a[k];
        float4 wv = *(const float4*)&w[(size_t)k*4096 + n4*4];
        acc.x += av*wv.x; acc.y += av*wv.y; acc.z += av*wv.z; acc.w += av*wv.w;
    }
    #pragma unroll 4
    for (int k = 0; k < 64; k++){
        float pv = pe[k];
        float4 wv = *(const float4*)&w[(size_t)(64+k)*4096 + n4*4];
        acc.x += pv*wv.x; acc.y += pv*wv.y; acc.z += pv*wv.z; acc.w += pv*wv.w;
    }
    sto4(&out[(size_t)t*4096 + n4*4], acc);
}

// ---------- weight transpose+convert: wt[n*K+k] = bf16(w[k*N+n]) ----------
__global__ __launch_bounds__(256) void k_wtr(const float* __restrict__ w,
    short* __restrict__ wt, int K, int N)
{
    int i = blockIdx.x*256 + threadIdx.x;
    if (i >= K*N) return;
    int n = i / K, k = i - n*K;
    wt[i] = f2bs(w[(size_t)k*N + n]);
}

// ---------- encoder 3-tap pool, f32, 4 ch/thread ----------
__global__ __launch_bounds__(256) void k_pool4(const float* __restrict__ xin,
    const int* __restrict__ col, const float* __restrict__ val, float* __restrict__ out,
    int total4, int c4mask, int cs, int vomask, int vos, int Vi)
{
    int i = blockIdx.x*256 + threadIdx.x;
    if (i >= total4) return;
    int c4 = i & c4mask;
    int rv = i >> cs;
    int r  = rv & vomask;
    int t  = rv >> vos;
    int C  = (c4mask + 1) << 2;
    const float* xt = xin + (size_t)t * Vi * C;
    int r3 = 3*r;
    int j0 = col[r3], j1 = col[r3+1], j2 = col[r3+2];
    float v0 = val[r3], v1 = val[r3+1], v2 = val[r3+2];
    int c = c4 << 2;
    float4 a = *(const float4*)&xt[(size_t)j0*C + c];
    float4 b = *(const float4*)&xt[(size_t)j1*C + c];
    float4 d = *(const float4*)&xt[(size_t)j2*C + c];
    float4 o;
    o.x = v0*a.x + v1*b.x + v2*d.x;
    o.y = v0*a.y + v1*b.y + v2*d.y;
    o.z = v0*a.z + v1*b.z + v2*d.z;
    o.w = v0*a.w + v1*b.w + v2*d.w;
    sto4(&out[(size_t)i << 2], o);
}

// ---------- decoder 3-tap pool, bf16 in/out, 8 ch/thread, t-swizzled ----------
__global__ __launch_bounds__(256) void k_poolb(const bf16* __restrict__ xin,
    const int* __restrict__ col, const float* __restrict__ val, bf16* __restrict__ out,
    int c8mask, int cs, int vom, int vshin, int cshift, int bs, int ept8)
{
    int t, rem; swz_t(blockIdx.x, bs, t, rem);
    int il = rem*256 + threadIdx.x;
    int c8 = il & c8mask;
    int r  = (il >> cs) & vom;
    size_t i = (size_t)t * ept8 + il;
    const bf16* xt = xin + ((size_t)t << (vshin + cshift));
    int r3 = 3*r;
    int j0 = col[r3], j1 = col[r3+1], j2 = col[r3+2];
    float v0 = val[r3], v1 = val[r3+1], v2 = val[r3+2];
    int c = c8 << 3;
    short8v a = *(const short8v*)&xt[((size_t)j0 << cshift) + c];
    short8v b = *(const short8v*)&xt[((size_t)j1 << cshift) + c];
    short8v d = *(const short8v*)&xt[((size_t)j2 << cshift) + c];
    short8v o;
    #pragma unroll
    for (int q = 0; q < 8; q++)
        o[q] = f2bs(v0*bsu2f(a[q]) + v1*bsu2f(b[q]) + v2*bsu2f(d[q]));
    *(short8v*)&out[i << 3] = o;
}

// ---------- unified MFMA(32x32x16) spiral conv + ELU ----------
// Per-64-K chunks (one 128-B row segment per A-row per chunk, coalesced staging),
// MT = 128*MTILES rows/block, one 32-col N-block per block, t-swizzled.
// A frag: m=lane&31, k=half*8+j ; B frag: n=lane&31. C/D: col=lane&31,
// row=(reg&3)+8*(reg>>2)+4*half  [verified m74/m101, rounds 8-9]
template<int KTOT, int CSHIFT, int NTOT, int MTILES, typename TOUT>
__global__ __launch_bounds__(256) void k_conv_s(
    const bf16* __restrict__ xin, const int* __restrict__ spiral,
    const short* __restrict__ wt, const float* __restrict__ bias, TOUT* __restrict__ out,
    int vshift, int bs, int nbshift)
{
    constexpr int MT  = 128*MTILES;
    constexpr int NCH = KTOT >> 6;
    constexpr int CSUB = CSHIFT - 6;
    __shared__ short lds_a[MT*72];
    __shared__ short lds_b[32*72];
    const int tid = threadIdx.x;
    const int lane = tid & 63;
    const int wv = tid >> 6;
    const int col = lane & 31;
    const int half = lane >> 5;

    int t, rem; swz_t(blockIdx.x, bs, t, rem);
    const int nb = rem & ((1 << nbshift) - 1);
    const int vt = rem >> nbshift;
    const int mbase = vt*MT;
    const size_t xslab = (size_t)t << (vshift + CSHIFT);

    f32x16 acc[MTILES];
    {
        float bv = bias[nb*32 + col];
        #pragma unroll
        for (int h = 0; h < MTILES; h++)
            #pragma unroll
            for (int r = 0; r < 16; r++) acc[h][r] = bv;
    }

    for (int ch = 0; ch < NCH; ch++){
        int s = ch >> CSUB;
        int coff = (ch & ((1 << CSUB) - 1)) << 6;
        __syncthreads();
        // stage A: MT rows x 64 k (8 threads per row, 128 B contiguous per row)
        #pragma unroll
        for (int e = tid; e < MT*8; e += 256){
            int m = e >> 3, kk = (e & 7) << 3;
            int vrow = mbase + m;
            int j = spiral[vrow*9 + s];
            *(short8v*)&lds_a[m*72 + kk] =
                *(const short8v*)&xin[xslab + ((size_t)j << CSHIFT) + coff + kk];
        }
        // stage B: 32 rows x 64 k (exactly 1 load/thread)
        {
            int n = tid >> 3, kk = (tid & 7) << 3;
            *(short8v*)&lds_b[n*72 + kk] =
                *(const short8v*)&wt[(size_t)(nb*32 + n)*KTOT + (ch << 6) + kk];
        }
        __syncthreads();
        #pragma unroll
        for (int ks = 0; ks < 4; ks++){
            short8v b = *(short8v*)&lds_b[col*72 + ks*16 + half*8];
            #pragma unroll
            for (int h = 0; h < MTILES; h++){
                short8v a = *(short8v*)&lds_a[(h*128 + wv*32 + col)*72 + ks*16 + half*8];
                acc[h] = __builtin_amdgcn_mfma_f32_32x32x16_bf16(a, b, acc[h], 0, 0, 0);
            }
        }
    }
    // epilogue
    #pragma unroll
    for (int h = 0; h < MTILES; h++){
        size_t mb = ((size_t)t << vshift) + mbase + h*128 + wv*32;
        #pragma unroll
        for (int r = 0; r < 16; r++){
            int row = (r & 3) + 8*(r >> 2) + 4*half;
            float vv = acc[h][r];
            vv = vv > 0.f ? vv : __expf(vv) - 1.f;
            sto(&out[(mb + row)*NTOT + nb*32 + col], vv);
        }
    }
}

// ---------- VALU spiral conv (encoder; tiny) ----------
template<typename TIN>
__global__ __launch_bounds__(256) void k_conv(const TIN* __restrict__ xin,
    const int* __restrict__ spiral, const float* __restrict__ w, const float* __restrict__ bias,
    float* __restrict__ out, int TV, int V, int vshift, int C, int O2, int o2shift,
    int K, int KP, int MT)
{
    extern __shared__ float lds[];
    const int S = 9;
    int tid = threadIdx.x;
    int O = O2 << 1;
    int gmbase = blockIdx.x * MT;

    int total = MT * K;
    for (int e = tid; e < total; e += 256){
        int m = e / K, k = e - m*K;
        int gm = gmbase + m;
        if (gm < TV){
            int t = gm >> vshift, v = gm & (V-1);
            int s = k / C, c = k - s*C;
            int jj = spiral[v*S + s];
            lds[m*KP + k] = tof(xin[((size_t)t*V + jj)*C + c]);
        }
    }
    __syncthreads();

    int m = tid >> o2shift;
    int o = tid & (O2 - 1);
    int gm = gmbase + m;
    if (gm >= TV) return;
    const float* g  = lds + m*KP;
    const float* wp = w + 2*o;
    float acc0 = bias[2*o];
    float acc1 = bias[2*o+1];
    int K4 = K & ~3;
    for (int k = 0; k < K4; k += 4){
        float4 g4 = *(const float4*)(g + k);
        float2 w0 = *(const float2*)(wp + (size_t)k    *O);
        float2 w1 = *(const float2*)(wp + (size_t)(k+1)*O);
        float2 w2 = *(const float2*)(wp + (size_t)(k+2)*O);
        float2 w3 = *(const float2*)(wp + (size_t)(k+3)*O);
        acc0 += g4.x*w0.x + g4.y*w1.x + g4.z*w2.x + g4.w*w3.x;
        acc1 += g4.x*w0.y + g4.y*w1.y + g4.z*w2.y + g4.w*w3.y;
    }
    for (int k = K4; k < K; k++){
        float gv = g[k];
        acc0 += gv * wp[(size_t)k*O];
        acc1 += gv * wp[(size_t)k*O + 1];
    }
    acc0 = acc0 > 0.f ? acc0 : __expf(acc0) - 1.f;
    acc1 = acc1 > 0.f ? acc1 : __expf(acc1) - 1.f;
    float2 r; r.x = acc0; r.y = acc1;
    *(float2*)(out + (size_t)gm*O + 2*o) = r;
}

// ---------- final conv (O=3, no ELU) + actor residual; bf16 input, 16-B gather ----------
__global__ __launch_bounds__(256) void k_outconv(const bf16* __restrict__ xin,
    const int* __restrict__ spiral, const float* __restrict__ w, const float* __restrict__ bias,
    const float* __restrict__ actor, float* __restrict__ out, int vshift, int bs)
{
    int t, rem; swz_t(blockIdx.x, bs, t, rem);
    int v = rem*256 + threadIdx.x;
    size_t i = ((size_t)t << vshift) + v;
    const bf16* xt = xin + (((size_t)t << vshift)) * 32;
    float a0 = bias[0], a1 = bias[1], a2 = bias[2];
    #pragma unroll
    for (int s = 0; s < 9; s++){
        int j = spiral[v*9 + s];
        const short8v* xr = (const short8v*)(xt + (size_t)j*32);
        #pragma unroll
        for (int h = 0; h < 4; h++){
            short8v sv = xr[h];
            const float* wr = w + (s*32 + h*8)*3;
            #pragma unroll
            for (int q = 0; q < 8; q++){
                float xv = bsu2f(sv[q]);
                a0 += xv * wr[q*3];
                a1 += xv * wr[q*3+1];
                a2 += xv * wr[q*3+2];
            }
        }
    }
    a0 += actor[v*3]; a1 += actor[v*3+1]; a2 += actor[v*3+2];
    out[i*3]   = a0;
    out[i*3+1] = a1;
    out[i*3+2] = a2;
}

extern "C" void kernel_launch(void* const* d_in, const int* in_sizes, int n_in,
                              void* d_out, int out_size, void* d_ws, size_t ws_size,
                              hipStream_t stream)
{
    (void)n_in; (void)out_size; (void)ws_size;
    const float* hs        = (const float*)d_in[0];
    const float* actor     = (const float*)d_in[1];
    const float* audio_w   = (const float*)d_in[2];
    const float* audio_b   = (const float*)d_in[3];
    const float* enc_w[4]  = {(const float*)d_in[4],(const float*)d_in[6],(const float*)d_in[8],(const float*)d_in[10]};
    const float* enc_b[4]  = {(const float*)d_in[5],(const float*)d_in[7],(const float*)d_in[9],(const float*)d_in[11]};
    const float* enc_lat_w = (const float*)d_in[12];
    const float* enc_lat_b = (const float*)d_in[13];
    const float* dec_lin_w = (const float*)d_in[14];
    const float* dec_lin_b = (const float*)d_in[15];
    const float* dec_w[4]  = {(const float*)d_in[16],(const float*)d_in[18],(const float*)d_in[20],(const float*)d_in[22]};
    const float* dec_b[4]  = {(const float*)d_in[17],(const float*)d_in[19],(const float*)d_in[21],(const float*)d_in[23]};
    const float* dec_out_w = (const float*)d_in[24];
    const float* dec_out_b = (const float*)d_in[25];
    const int*   spiral[4] = {(const int*)d_in[26],(const int*)d_in[27],(const int*)d_in[28],(const int*)d_in[29]};

    const int* dcol[4]; const float* dval[4]; const int* ucol[4]; const float* uval[4];
    bool interleaved = (in_sizes[33] == 3*8192);
    for (int i = 0; i < 4; i++){
        if (interleaved){
            int b = 30 + 6*i;
            dcol[i] = (const int*)d_in[b+1]; dval[i] = (const float*)d_in[b+2];
            ucol[i] = (const int*)d_in[b+4]; uval[i] = (const float*)d_in[b+5];
        } else {
            dcol[i] = (const int*)d_in[31+3*i]; dval[i] = (const float*)d_in[32+3*i];
            ucol[i] = (const int*)d_in[43+3*i]; uval[i] = (const float*)d_in[44+3*i];
        }
    }

    // ---- workspace ----
    char* ws = (char*)d_ws;
    size_t off = 0;
    auto alloc = [&](size_t bytes)->char* {
        char* p = ws + off; off += (bytes + 255) & ~(size_t)255; return p;
    };
    float* encX0 = (float*)alloc((size_t)262144*4);
    float* encP0 = (float*)alloc((size_t)65536*4);
    float* encX1 = (float*)alloc((size_t)131072*4);
    float* encP1 = (float*)alloc((size_t)32768*4);
    float* encX2 = (float*)alloc((size_t)32768*4);
    float* encP2 = (float*)alloc((size_t)8192*4);
    float* encX3 = (float*)alloc((size_t)16384*4);
    float* encP3 = (float*)alloc((size_t)4096*4);
    float* aemb  = (float*)alloc((size_t)4096*4);
    float* pemb  = (float*)alloc((size_t)64*4);
    short* wt0   = (short*)alloc((size_t)147456*2);   // dec0 [128][1152]
    short* wt1   = (short*)alloc((size_t)73728*2);    // dec1 [64][1152]
    short* wt2   = (short*)alloc((size_t)36864*2);    // dec2 [64][576]
    short* wt3   = (short*)alloc((size_t)18432*2);    // dec3 [32][576]
    bf16*  Pb    = (bf16*)alloc((size_t)36*1048576);  // conv/declin outputs
    bf16*  Qb    = (bf16*)alloc((size_t)68*1048576);  // pool outputs

    // ---- prep ----
    k_audio<<<64,64,0,stream>>>(hs, audio_w, audio_b, aemb);
    k_wtr<<<576,256,0,stream>>>(dec_w[0], wt0, 1152, 128);
    k_wtr<<<288,256,0,stream>>>(dec_w[1], wt1, 1152, 64);
    k_wtr<<<144,256,0,stream>>>(dec_w[2], wt2, 576, 64);
    k_wtr<<<72,256,0,stream>>>(dec_w[3], wt3, 576, 32);

    // ---- encoder (VALU; tiny, B=1) ----
    k_conv<float><<<512,256, 16*28*4, stream>>>(actor, spiral[0], enc_w[0], enc_b[0], encX0, 8192, 8192,13,   3,16,4,  27,  28,16);
    k_pool4<<<64,256,0,stream>>>(encX0, dcol[0], dval[0], encP0, 16384, 7,3, 2047,11, 8192);
    k_conv<float><<<256,256, 8*292*4, stream>>>(encP0, spiral[1], enc_w[1], enc_b[1], encX1, 2048, 2048,11,  32,32,5, 288, 292, 8);
    k_pool4<<<32,256,0,stream>>>(encX1, dcol[1], dval[1], encP1, 8192, 15,4, 511,9, 2048);
    k_conv<float><<<64,256, 8*580*4, stream>>>(encP1, spiral[2], enc_w[2], enc_b[2], encX2, 512, 512,9,  64,32,5, 576, 580, 8);
    k_pool4<<<8,256,0,stream>>>(encX2, dcol[2], dval[2], encP2, 2048, 15,4, 127,7, 512);
    k_conv<float><<<32,256, 4*580*4, stream>>>(encP2, spiral[3], enc_w[3], enc_b[3], encX3, 128, 128,7,  64,64,6, 576, 580, 4);
    k_pool4<<<4,256,0,stream>>>(encX3, dcol[3], dval[3], encP3, 1024, 31,5, 31,5, 128);
    k_enclat<<<64,256,0,stream>>>(encP3, enc_lat_w, enc_lat_b, pemb);

    // ---- decoder (XCD t-swizzled, all-bf16) ----
    k_declin4<<<dim3(4,64),256,0,stream>>>(aemb, pemb, dec_lin_w, dec_lin_b, Pb);           // ->[64][32][128] bf16

    k_poolb<<<512,256,0,stream>>>(Pb, ucol[3], uval[3], Qb, 15,4, 127, 5,7, 3, 2048);        // ->[64][128][128]
    k_conv_s<1152,7,128,1,bf16><<<256,256,0,stream>>>(Qb, spiral[3], wt0, dec_b[0], Pb, 7, 2, 2);   // ->[64][128][128]

    k_poolb<<<2048,256,0,stream>>>(Pb, ucol[2], uval[2], Qb, 15,4, 511, 7,7, 5, 8192);       // ->[64][512][128]
    k_conv_s<1152,7,64,2,bf16><<<256,256,0,stream>>>(Qb, spiral[2], wt1, dec_b[1], Pb, 9, 2, 1);    // ->[64][512][64]

    k_poolb<<<4096,256,0,stream>>>(Pb, ucol[1], uval[1], Qb, 7,3, 2047, 9,6, 6, 16384);      // ->[64][2048][64]
    k_conv_s<576,6,64,2,bf16><<<1024,256,0,stream>>>(Qb, spiral[1], wt2, dec_b[2], Pb, 11, 4, 1);   // ->[64][2048][64]

    k_poolb<<<16384,256,0,stream>>>(Pb, ucol[0], uval[0], Qb, 7,3, 8191, 11,6, 8, 65536);    // ->[64][8192][64]
    k_conv_s<576,6,32,2,bf16><<<2048,256,0,stream>>>(Qb, spiral[0], wt3, dec_b[3], Pb, 13, 5, 0);   // ->[64][8192][32]

    k_outconv<<<2048,256,0,stream>>>(Pb, spiral[0], dec_out_w, dec_out_b, actor, (float*)d_out, 13, 5);
}

// Round 11
// 529.156 us; speedup vs baseline: 1.1594x; 1.1594x over previous
//
#include <hip/hip_runtime.h>
#include <hip/hip_bf16.h>

typedef __hip_bfloat16 bf16;
typedef __attribute__((ext_vector_type(8))) short short8v;
typedef __attribute__((ext_vector_type(16))) float f32x16;

__device__ __forceinline__ float tof(float v){ return v; }
__device__ __forceinline__ float tof(bf16 v){ return __bfloat162float(v); }
__device__ __forceinline__ void sto(float* p, float v){ *p = v; }
__device__ __forceinline__ void sto(bf16* p, float v){ *p = __float2bfloat16(v); }
__device__ __forceinline__ short f2bs(float f){ bf16 h = __float2bfloat16(f); return *(short*)&h; }
__device__ __forceinline__ float bsu2f(short s){
    return __uint_as_float(((unsigned)(unsigned short)s) << 16);
}

__device__ __forceinline__ void sto4(float* p, float4 v){ *(float4*)p = v; }
__device__ __forceinline__ void sto4(bf16* p, float4 v){
    short4 s; s.x=f2bs(v.x); s.y=f2bs(v.y); s.z=f2bs(v.z); s.w=f2bs(v.w);
    *(short4*)p = s;
}

// XCD-aware swizzle for 64-frame (t) problems: grid = 64 << bs blocks.
__device__ __forceinline__ void swz_t(int b, int bs, int& t, int& rem){
    int x = b & 7, k = b >> 3;
    t = x*8 + (k >> bs);
    rem = k & ((1 << bs) - 1);
}

// ---------- fused prep: 4 weight transposes + audio embedding ----------
__global__ __launch_bounds__(256) void k_prep(
    const float* __restrict__ w0, const float* __restrict__ w1,
    const float* __restrict__ w2, const float* __restrict__ w3,
    short* __restrict__ wt0, short* __restrict__ wt1,
    short* __restrict__ wt2, short* __restrict__ wt3,
    const float* __restrict__ hs, const float* __restrict__ aw,
    const float* __restrict__ ab, float* __restrict__ aemb)
{
    int b = blockIdx.x, tid = threadIdx.x;
    if (b < 1080){
        const float* w; short* wt; int K, N, i;
        if      (b < 576) { w = w0; wt = wt0; K = 1152; N = 128; i = b*256 + tid; }
        else if (b < 864) { w = w1; wt = wt1; K = 1152; N = 64;  i = (b-576)*256 + tid; }
        else if (b < 1008){ w = w2; wt = wt2; K = 576;  N = 64;  i = (b-864)*256 + tid; }
        else              { w = w3; wt = wt3; K = 576;  N = 32;  i = (b-1008)*256 + tid; }
        int n = i / K, k = i - n*K;
        wt[i] = f2bs(w[(size_t)k*N + n]);
    } else {
        int idx = (b - 1080)*256 + tid;      // 0..4095
        int t = idx >> 6, l = idx & 63;
        float acc = ab[l];
        const float* h = hs + t*768;
        #pragma unroll 4
        for (int k = 0; k < 768; k++) acc += h[k] * aw[k*64 + l];
        aemb[t*64 + l] = acc;
    }
}

// ---------- enc_lat ----------
__global__ __launch_bounds__(256) void k_enclat(const float* __restrict__ flat,
    const float* __restrict__ w, const float* __restrict__ b, float* __restrict__ out)
{
    __shared__ float red[256];
    int l = blockIdx.x, tid = threadIdx.x;
    float acc = 0.f;
    for (int k = tid; k < 4096; k += 256) acc += flat[k] * w[k*64 + l];
    red[tid] = acc; __syncthreads();
    for (int s = 128; s > 0; s >>= 1){ if (tid < s) red[tid] += red[tid+s]; __syncthreads(); }
    if (tid == 0) out[l] = red[0] + b[l];
}

// ---------- dec_lin fused with latent concat; bf16 out [t][32][128] ----------
__global__ __launch_bounds__(256) void k_declin4(const float* __restrict__ ae,
    const float* __restrict__ pe, const float* __restrict__ w, const float* __restrict__ b,
    bf16* __restrict__ out)
{
    int n4 = blockIdx.x*256 + threadIdx.x;   // 0..1023
    int t = blockIdx.y;
    float4 acc = *(const float4*)&b[n4*4];
    const float* a = ae + t*64;
    #pragma unroll 4
    for (int k = 0; k < 64; k++){
        float av = a[k];
        float4 wv = *(const float4*)&w[(size_t)k*4096 + n4*4];
        acc.x += av*wv.x; acc.y += av*wv.y; acc.z += av*wv.z; acc.w += av*wv.w;
    }
    #pragma unroll 4
    for (int k = 0; k < 64; k++){
        float pv = pe[k];
        float4 wv = *(const float4*)&w[(size_t)(64+k)*4096 + n4*4];
        acc.x += pv*wv.x; acc.y += pv*wv.y; acc.z += pv*wv.z; acc.w += pv*wv.w;
    }
    sto4(&out[(size_t)t*4096 + n4*4], acc);
}

// ---------- encoder 3-tap pool, f32, 4 ch/thread ----------
__global__ __launch_bounds__(256) void k_pool4(const float* __restrict__ xin,
    const int* __restrict__ col, const float* __restrict__ val, float* __restrict__ out,
    int total4, int c4mask, int cs, int vomask, int vos, int Vi)
{
    int i = blockIdx.x*256 + threadIdx.x;
    if (i >= total4) return;
    int c4 = i & c4mask;
    int rv = i >> cs;
    int r  = rv & vomask;
    int t  = rv >> vos;
    int C  = (c4mask + 1) << 2;
    const float* xt = xin + (size_t)t * Vi * C;
    int r3 = 3*r;
    int j0 = col[r3], j1 = col[r3+1], j2 = col[r3+2];
    float v0 = val[r3], v1 = val[r3+1], v2 = val[r3+2];
    int c = c4 << 2;
    float4 a = *(const float4*)&xt[(size_t)j0*C + c];
    float4 b = *(const float4*)&xt[(size_t)j1*C + c];
    float4 d = *(const float4*)&xt[(size_t)j2*C + c];
    float4 o;
    o.x = v0*a.x + v1*b.x + v2*d.x;
    o.y = v0*a.y + v1*b.y + v2*d.y;
    o.z = v0*a.z + v1*b.z + v2*d.z;
    o.w = v0*a.w + v1*b.w + v2*d.w;
    sto4(&out[(size_t)i << 2], o);
}

// ---------- decoder 3-tap pool, bf16 in/out, 8 ch/thread, t-swizzled ----------
__global__ __launch_bounds__(256) void k_poolb(const bf16* __restrict__ xin,
    const int* __restrict__ col, const float* __restrict__ val, bf16* __restrict__ out,
    int c8mask, int cs, int vom, int vshin, int cshift, int bs, int ept8)
{
    int t, rem; swz_t(blockIdx.x, bs, t, rem);
    int il = rem*256 + threadIdx.x;
    int c8 = il & c8mask;
    int r  = (il >> cs) & vom;
    size_t i = (size_t)t * ept8 + il;
    const bf16* xt = xin + ((size_t)t << (vshin + cshift));
    int r3 = 3*r;
    int j0 = col[r3], j1 = col[r3+1], j2 = col[r3+2];
    float v0 = val[r3], v1 = val[r3+1], v2 = val[r3+2];
    int c = c8 << 3;
    short8v a = *(const short8v*)&xt[((size_t)j0 << cshift) + c];
    short8v b = *(const short8v*)&xt[((size_t)j1 << cshift) + c];
    short8v d = *(const short8v*)&xt[((size_t)j2 << cshift) + c];
    short8v o;
    #pragma unroll
    for (int q = 0; q < 8; q++)
        o[q] = f2bs(v0*bsu2f(a[q]) + v1*bsu2f(b[q]) + v2*bsu2f(d[q]));
    *(short8v*)&out[i << 3] = o;
}

// ---------- pipelined MFMA(32x32x16) spiral conv + ELU ----------
// Register-prefetch double buffer: chunk ch+1's global loads are issued into
// VGPRs before chunk ch's compute, committed to LDS after the barrier.
// A frag: m=lane&31, k=half*8+j ; B frag: n=lane&31. C/D: col=lane&31,
// row=(reg&3)+8*(reg>>2)+4*half  [verified m74/m101, rounds 8-10]
template<int KTOT, int CSHIFT, int NTOT, int MTILES, typename TOUT>
__global__ __launch_bounds__(256) void k_conv_p(
    const bf16* __restrict__ xin, const int* __restrict__ spiral,
    const short* __restrict__ wt, const float* __restrict__ bias, TOUT* __restrict__ out,
    int vshift, int bs, int nbshift)
{
    constexpr int MT   = 128*MTILES;
    constexpr int NCH  = KTOT >> 6;
    constexpr int CSUB = CSHIFT - 6;
    constexpr int AU   = MT*8/256;     // A prefetch regs per thread
    __shared__ short lds_a[MT*72];
    __shared__ short lds_b[32*72];
    const int tid = threadIdx.x;
    const int lane = tid & 63;
    const int wv = tid >> 6;
    const int col = lane & 31;
    const int half = lane >> 5;

    int t, rem; swz_t(blockIdx.x, bs, t, rem);
    const int nb = rem & ((1 << nbshift) - 1);
    const int vt = rem >> nbshift;
    const int mbase = vt*MT;
    const size_t xslab = (size_t)t << (vshift + CSHIFT);

    short8v pa[AU];
    short8v pb;
    const int am = tid >> 3;               // A row handled by this thread (base)
    const int ak = (tid & 7) << 3;         // A k-offset within chunk
    const int bn = tid >> 3;               // B row
    const int bk = (tid & 7) << 3;

    auto issue = [&](int ch){
        int s = ch >> CSUB;
        int coff = ((ch & ((1 << CSUB) - 1)) << 6) + ak;
        #pragma unroll
        for (int u = 0; u < AU; u++){
            int j = spiral[(mbase + am + u*32)*9 + s];
            pa[u] = *(const short8v*)&xin[xslab + ((size_t)j << CSHIFT) + coff];
        }
        pb = *(const short8v*)&wt[(size_t)(nb*32 + bn)*KTOT + (ch << 6) + bk];
    };
    auto commit = [&](){
        #pragma unroll
        for (int u = 0; u < AU; u++)
            *(short8v*)&lds_a[(am + u*32)*72 + ak] = pa[u];
        *(short8v*)&lds_b[bn*72 + bk] = pb;
    };

    f32x16 acc[MTILES];
    {
        float bv = bias[nb*32 + col];
        #pragma unroll
        for (int h = 0; h < MTILES; h++)
            #pragma unroll
            for (int r = 0; r < 16; r++) acc[h][r] = bv;
    }

    issue(0);
    commit();
    __syncthreads();
    for (int ch = 0; ch < NCH; ch++){
        if (ch + 1 < NCH) issue(ch + 1);   // loads in flight during compute
        #pragma unroll
        for (int ks = 0; ks < 4; ks++){
            short8v b = *(short8v*)&lds_b[col*72 + ks*16 + half*8];
            #pragma unroll
            for (int h = 0; h < MTILES; h++){
                short8v a = *(short8v*)&lds_a[(h*128 + wv*32 + col)*72 + ks*16 + half*8];
                acc[h] = __builtin_amdgcn_mfma_f32_32x32x16_bf16(a, b, acc[h], 0, 0, 0);
            }
        }
        __syncthreads();                   // all waves done reading LDS
        if (ch + 1 < NCH){
            commit();                      // vmcnt wait lands here, after compute
            __syncthreads();
        }
    }
    // epilogue
    #pragma unroll
    for (int h = 0; h < MTILES; h++){
        size_t mb = ((size_t)t << vshift) + mbase + h*128 + wv*32;
        #pragma unroll
        for (int r = 0; r < 16; r++){
            int row = (r & 3) + 8*(r >> 2) + 4*half;
            float vv = acc[h][r];
            vv = vv > 0.f ? vv : __expf(vv) - 1.f;
            sto(&out[(mb + row)*NTOT + nb*32 + col], vv);
        }
    }
}

// ---------- VALU spiral conv (encoder; tiny) ----------
template<typename TIN>
__global__ __launch_bounds__(256) void k_conv(const TIN* __restrict__ xin,
    const int* __restrict__ spiral, const float* __restrict__ w, const float* __restrict__ bias,
    float* __restrict__ out, int TV, int V, int vshift, int C, int O2, int o2shift,
    int K, int KP, int MT)
{
    extern __shared__ float lds[];
    const int S = 9;
    int tid = threadIdx.x;
    int O = O2 << 1;
    int gmbase = blockIdx.x * MT;

    int total = MT * K;
    for (int e = tid; e < total; e += 256){
        int m = e / K, k = e - m*K;
        int gm = gmbase + m;
        if (gm < TV){
            int t = gm >> vshift, v = gm & (V-1);
            int s = k / C, c = k - s*C;
            int jj = spiral[v*S + s];
            lds[m*KP + k] = tof(xin[((size_t)t*V + jj)*C + c]);
        }
    }
    __syncthreads();

    int m = tid >> o2shift;
    int o = tid & (O2 - 1);
    int gm = gmbase + m;
    if (gm >= TV) return;
    const float* g  = lds + m*KP;
    const float* wp = w + 2*o;
    float acc0 = bias[2*o];
    float acc1 = bias[2*o+1];
    int K4 = K & ~3;
    for (int k = 0; k < K4; k += 4){
        float4 g4 = *(const float4*)(g + k);
        float2 w0 = *(const float2*)(wp + (size_t)k    *O);
        float2 w1 = *(const float2*)(wp + (size_t)(k+1)*O);
        float2 w2 = *(const float2*)(wp + (size_t)(k+2)*O);
        float2 w3 = *(const float2*)(wp + (size_t)(k+3)*O);
        acc0 += g4.x*w0.x + g4.y*w1.x + g4.z*w2.x + g4.w*w3.x;
        acc1 += g4.x*w0.y + g4.y*w1.y + g4.z*w2.y + g4.w*w3.y;
    }
    for (int k = K4; k < K; k++){
        float gv = g[k];
        acc0 += gv * wp[(size_t)k*O];
        acc1 += gv * wp[(size_t)k*O + 1];
    }
    acc0 = acc0 > 0.f ? acc0 : __expf(acc0) - 1.f;
    acc1 = acc1 > 0.f ? acc1 : __expf(acc1) - 1.f;
    float2 r; r.x = acc0; r.y = acc1;
    *(float2*)(out + (size_t)gm*O + 2*o) = r;
}

// ---------- final conv (O=3, no ELU) + actor residual; bf16 input, 16-B gather ----------
__global__ __launch_bounds__(256) void k_outconv(const bf16* __restrict__ xin,
    const int* __restrict__ spiral, const float* __restrict__ w, const float* __restrict__ bias,
    const float* __restrict__ actor, float* __restrict__ out, int vshift, int bs)
{
    int t, rem; swz_t(blockIdx.x, bs, t, rem);
    int v = rem*256 + threadIdx.x;
    size_t i = ((size_t)t << vshift) + v;
    const bf16* xt = xin + (((size_t)t << vshift)) * 32;
    float a0 = bias[0], a1 = bias[1], a2 = bias[2];
    #pragma unroll
    for (int s = 0; s < 9; s++){
        int j = spiral[v*9 + s];
        const short8v* xr = (const short8v*)(xt + (size_t)j*32);
        #pragma unroll
        for (int h = 0; h < 4; h++){
            short8v sv = xr[h];
            const float* wr = w + (s*32 + h*8)*3;
            #pragma unroll
            for (int q = 0; q < 8; q++){
                float xv = bsu2f(sv[q]);
                a0 += xv * wr[q*3];
                a1 += xv * wr[q*3+1];
                a2 += xv * wr[q*3+2];
            }
        }
    }
    a0 += actor[v*3]; a1 += actor[v*3+1]; a2 += actor[v*3+2];
    out[i*3]   = a0;
    out[i*3+1] = a1;
    out[i*3+2] = a2;
}

extern "C" void kernel_launch(void* const* d_in, const int* in_sizes, int n_in,
                              void* d_out, int out_size, void* d_ws, size_t ws_size,
                              hipStream_t stream)
{
    (void)n_in; (void)out_size; (void)ws_size;
    const float* hs        = (const float*)d_in[0];
    const float* actor     = (const float*)d_in[1];
    const float* audio_w   = (const float*)d_in[2];
    const float* audio_b   = (const float*)d_in[3];
    const float* enc_w[4]  = {(const float*)d_in[4],(const float*)d_in[6],(const float*)d_in[8],(const float*)d_in[10]};
    const float* enc_b[4]  = {(const float*)d_in[5],(const float*)d_in[7],(const float*)d_in[9],(const float*)d_in[11]};
    const float* enc_lat_w = (const float*)d_in[12];
    const float* enc_lat_b = (const float*)d_in[13];
    const float* dec_lin_w = (const float*)d_in[14];
    const float* dec_lin_b = (const float*)d_in[15];
    const float* dec_w[4]  = {(const float*)d_in[16],(const float*)d_in[18],(const float*)d_in[20],(const float*)d_in[22]};
    const float* dec_b[4]  = {(const float*)d_in[17],(const float*)d_in[19],(const float*)d_in[21],(const float*)d_in[23]};
    const float* dec_out_w = (const float*)d_in[24];
    const float* dec_out_b = (const float*)d_in[25];
    const int*   spiral[4] = {(const int*)d_in[26],(const int*)d_in[27],(const int*)d_in[28],(const int*)d_in[29]};

    const int* dcol[4]; const float* dval[4]; const int* ucol[4]; const float* uval[4];
    bool interleaved = (in_sizes[33] == 3*8192);
    for (int i = 0; i < 4; i++){
        if (interleaved){
            int b = 30 + 6*i;
            dcol[i] = (const int*)d_in[b+1]; dval[i] = (const float*)d_in[b+2];
            ucol[i] = (const int*)d_in[b+4]; uval[i] = (const float*)d_in[b+5];
        } else {
            dcol[i] = (const int*)d_in[31+3*i]; dval[i] = (const float*)d_in[32+3*i];
            ucol[i] = (const int*)d_in[43+3*i]; uval[i] = (const float*)d_in[44+3*i];
        }
    }

    // ---- workspace ----
    char* ws = (char*)d_ws;
    size_t off = 0;
    auto alloc = [&](size_t bytes)->char* {
        char* p = ws + off; off += (bytes + 255) & ~(size_t)255; return p;
    };
    float* encX0 = (float*)alloc((size_t)262144*4);
    float* encP0 = (float*)alloc((size_t)65536*4);
    float* encX1 = (float*)alloc((size_t)131072*4);
    float* encP1 = (float*)alloc((size_t)32768*4);
    float* encX2 = (float*)alloc((size_t)32768*4);
    float* encP2 = (float*)alloc((size_t)8192*4);
    float* encX3 = (float*)alloc((size_t)16384*4);
    float* encP3 = (float*)alloc((size_t)4096*4);
    float* aemb  = (float*)alloc((size_t)4096*4);
    float* pemb  = (float*)alloc((size_t)64*4);
    short* wt0   = (short*)alloc((size_t)147456*2);   // dec0 [128][1152]
    short* wt1   = (short*)alloc((size_t)73728*2);    // dec1 [64][1152]
    short* wt2   = (short*)alloc((size_t)36864*2);    // dec2 [64][576]
    short* wt3   = (short*)alloc((size_t)18432*2);    // dec3 [32][576]
    bf16*  Pb    = (bf16*)alloc((size_t)36*1048576);  // conv/declin outputs
    bf16*  Qb    = (bf16*)alloc((size_t)68*1048576);  // pool outputs

    // ---- prep (fused) ----
    k_prep<<<1096,256,0,stream>>>(dec_w[0], dec_w[1], dec_w[2], dec_w[3],
                                  wt0, wt1, wt2, wt3, hs, audio_w, audio_b, aemb);

    // ---- encoder (VALU; tiny, B=1) ----
    k_conv<float><<<512,256, 16*28*4, stream>>>(actor, spiral[0], enc_w[0], enc_b[0], encX0, 8192, 8192,13,   3,16,4,  27,  28,16);
    k_pool4<<<64,256,0,stream>>>(encX0, dcol[0], dval[0], encP0, 16384, 7,3, 2047,11, 8192);
    k_conv<float><<<256,256, 8*292*4, stream>>>(encP0, spiral[1], enc_w[1], enc_b[1], encX1, 2048, 2048,11,  32,32,5, 288, 292, 8);
    k_pool4<<<32,256,0,stream>>>(encX1, dcol[1], dval[1], encP1, 8192, 15,4, 511,9, 2048);
    k_conv<float><<<64,256, 8*580*4, stream>>>(encP1, spiral[2], enc_w[2], enc_b[2], encX2, 512, 512,9,  64,32,5, 576, 580, 8);
    k_pool4<<<8,256,0,stream>>>(encX2, dcol[2], dval[2], encP2, 2048, 15,4, 127,7, 512);
    k_conv<float><<<32,256, 4*580*4, stream>>>(encP2, spiral[3], enc_w[3], enc_b[3], encX3, 128, 128,7,  64,64,6, 576, 580, 4);
    k_pool4<<<4,256,0,stream>>>(encX3, dcol[3], dval[3], encP3, 1024, 31,5, 31,5, 128);
    k_enclat<<<64,256,0,stream>>>(encP3, enc_lat_w, enc_lat_b, pemb);

    // ---- decoder (XCD t-swizzled, all-bf16, pipelined convs) ----
    k_declin4<<<dim3(4,64),256,0,stream>>>(aemb, pemb, dec_lin_w, dec_lin_b, Pb);           // ->[64][32][128] bf16

    k_poolb<<<512,256,0,stream>>>(Pb, ucol[3], uval[3], Qb, 15,4, 127, 5,7, 3, 2048);        // ->[64][128][128]
    k_conv_p<1152,7,128,1,bf16><<<256,256,0,stream>>>(Qb, spiral[3], wt0, dec_b[0], Pb, 7, 2, 2);   // ->[64][128][128]

    k_poolb<<<2048,256,0,stream>>>(Pb, ucol[2], uval[2], Qb, 15,4, 511, 7,7, 5, 8192);       // ->[64][512][128]
    k_conv_p<1152,7,64,2,bf16><<<256,256,0,stream>>>(Qb, spiral[2], wt1, dec_b[1], Pb, 9, 2, 1);    // ->[64][512][64]

    k_poolb<<<4096,256,0,stream>>>(Pb, ucol[1], uval[1], Qb, 7,3, 2047, 9,6, 6, 16384);      // ->[64][2048][64]
    k_conv_p<576,6,64,2,bf16><<<1024,256,0,stream>>>(Qb, spiral[1], wt2, dec_b[2], Pb, 11, 4, 1);   // ->[64][2048][64]

    k_poolb<<<16384,256,0,stream>>>(Pb, ucol[0], uval[0], Qb, 7,3, 8191, 11,6, 8, 65536);    // ->[64][8192][64]
    k_conv_p<576,6,32,2,bf16><<<2048,256,0,stream>>>(Qb, spiral[0], wt3, dec_b[3], Pb, 13, 5, 0);   // ->[64][8192][32]

    k_outconv<<<2048,256,0,stream>>>(Pb, spiral[0], dec_out_w, dec_out_b, actor, (float*)d_out, 13, 5);
}

// Round 12
// 486.622 us; speedup vs baseline: 1.2608x; 1.0874x over previous
//
#include <hip/hip_runtime.h>
#include <hip/hip_bf16.h>

typedef __hip_bfloat16 bf16;
typedef __attribute__((ext_vector_type(8))) short short8v;
typedef __attribute__((ext_vector_type(16))) float f32x16;

__device__ __forceinline__ float tof(float v){ return v; }
__device__ __forceinline__ float tof(bf16 v){ return __bfloat162float(v); }
__device__ __forceinline__ void sto(float* p, float v){ *p = v; }
__device__ __forceinline__ void sto(bf16* p, float v){ *p = __float2bfloat16(v); }
__device__ __forceinline__ short f2bs(float f){ bf16 h = __float2bfloat16(f); return *(short*)&h; }
__device__ __forceinline__ float bsu2f(short s){
    return __uint_as_float(((unsigned)(unsigned short)s) << 16);
}

__device__ __forceinline__ void sto4(float* p, float4 v){ *(float4*)p = v; }
__device__ __forceinline__ void sto4(bf16* p, float4 v){
    short4 s; s.x=f2bs(v.x); s.y=f2bs(v.y); s.z=f2bs(v.z); s.w=f2bs(v.w);
    *(short4*)p = s;
}

// XCD-aware swizzle for 64-frame (t) problems: grid = 64 << bs blocks.
__device__ __forceinline__ void swz_t(int b, int bs, int& t, int& rem){
    int x = b & 7, k = b >> 3;
    t = x*8 + (k >> bs);
    rem = k & ((1 << bs) - 1);
}

// ---------- fused prep: 4 weight transposes (coalesced read / scattered write)
// + audio embedding (block-per-t, 4x64 LDS reduce) ----------
__global__ __launch_bounds__(256) void k_prep(
    const float* __restrict__ w0, const float* __restrict__ w1,
    const float* __restrict__ w2, const float* __restrict__ w3,
    short* __restrict__ wt0, short* __restrict__ wt1,
    short* __restrict__ wt2, short* __restrict__ wt3,
    const float* __restrict__ hs, const float* __restrict__ aw,
    const float* __restrict__ ab, float* __restrict__ aemb)
{
    __shared__ float red[4][64];
    int b = blockIdx.x, tid = threadIdx.x;
    if (b < 1080){
        // i indexes the SOURCE (contiguous): coalesced read, scattered 2-B write.
        const float* w; short* wt; int K, nsh, i;
        if      (b < 576) { w = w0; wt = wt0; K = 1152; nsh = 7; i = b*256 + tid; }
        else if (b < 864) { w = w1; wt = wt1; K = 1152; nsh = 6; i = (b-576)*256 + tid; }
        else if (b < 1008){ w = w2; wt = wt2; K = 576;  nsh = 6; i = (b-864)*256 + tid; }
        else              { w = w3; wt = wt3; K = 576;  nsh = 5; i = (b-1008)*256 + tid; }
        int k = i >> nsh, n = i & ((1 << nsh) - 1);
        wt[n*K + k] = f2bs(w[i]);
    } else {
        int t = b - 1080;                    // 0..63
        int kg = tid >> 6, l = tid & 63;
        const float* h = hs + t*768;
        float acc = 0.f;
        int k0 = kg*192;
        #pragma unroll 8
        for (int k = k0; k < k0 + 192; k++) acc += h[k] * aw[k*64 + l];
        red[kg][l] = acc;
        __syncthreads();
        if (kg == 0)
            aemb[t*64 + l] = red[0][l] + red[1][l] + red[2][l] + red[3][l] + ab[l];
    }
}

// ---------- enc_lat ----------
__global__ __launch_bounds__(256) void k_enclat(const float* __restrict__ flat,
    const float* __restrict__ w, const float* __restrict__ b, float* __restrict__ out)
{
    __shared__ float red[256];
    int l = blockIdx.x, tid = threadIdx.x;
    float acc = 0.f;
    for (int k = tid; k < 4096; k += 256) acc += flat[k] * w[k*64 + l];
    red[tid] = acc; __syncthreads();
    for (int s = 128; s > 0; s >>= 1){ if (tid < s) red[tid] += red[tid+s]; __syncthreads(); }
    if (tid == 0) out[l] = red[0] + b[l];
}

// ---------- dec_lin fused with latent concat; bf16 out [t][32][128] ----------
__global__ __launch_bounds__(256) void k_declin4(const float* __restrict__ ae,
    const float* __restrict__ pe, const float* __restrict__ w, const float* __restrict__ b,
    bf16* __restrict__ out)
{
    int n4 = blockIdx.x*256 + threadIdx.x;   // 0..1023
    int t = blockIdx.y;
    float4 acc = *(const float4*)&b[n4*4];
    const float* a = ae + t*64;
    #pragma unroll 4
    for (int k = 0; k < 64; k++){
        float av = a[k];
        float4 wv = *(const float4*)&w[(size_t)k*4096 + n4*4];
        acc.x += av*wv.x; acc.y += av*wv.y; acc.z += av*wv.z; acc.w += av*wv.w;
    }
    #pragma unroll 4
    for (int k = 0; k < 64; k++){
        float pv = pe[k];
        float4 wv = *(const float4*)&w[(size_t)(64+k)*4096 + n4*4];
        acc.x += pv*wv.x; acc.y += pv*wv.y; acc.z += pv*wv.z; acc.w += pv*wv.w;
    }
    sto4(&out[(size_t)t*4096 + n4*4], acc);
}

// ---------- encoder 3-tap pool, f32, 4 ch/thread ----------
__global__ __launch_bounds__(256) void k_pool4(const float* __restrict__ xin,
    const int* __restrict__ col, const float* __restrict__ val, float* __restrict__ out,
    int total4, int c4mask, int cs, int vomask, int vos, int Vi)
{
    int i = blockIdx.x*256 + threadIdx.x;
    if (i >= total4) return;
    int c4 = i & c4mask;
    int rv = i >> cs;
    int r  = rv & vomask;
    int t  = rv >> vos;
    int C  = (c4mask + 1) << 2;
    const float* xt = xin + (size_t)t * Vi * C;
    int r3 = 3*r;
    int j0 = col[r3], j1 = col[r3+1], j2 = col[r3+2];
    float v0 = val[r3], v1 = val[r3+1], v2 = val[r3+2];
    int c = c4 << 2;
    float4 a = *(const float4*)&xt[(size_t)j0*C + c];
    float4 b = *(const float4*)&xt[(size_t)j1*C + c];
    float4 d = *(const float4*)&xt[(size_t)j2*C + c];
    float4 o;
    o.x = v0*a.x + v1*b.x + v2*d.x;
    o.y = v0*a.y + v1*b.y + v2*d.y;
    o.z = v0*a.z + v1*b.z + v2*d.z;
    o.w = v0*a.w + v1*b.w + v2*d.w;
    sto4(&out[(size_t)i << 2], o);
}

// ---------- decoder 3-tap pool, bf16 in/out, 8 ch/thread, t-swizzled ----------
__global__ __launch_bounds__(256) void k_poolb(const bf16* __restrict__ xin,
    const int* __restrict__ col, const float* __restrict__ val, bf16* __restrict__ out,
    int c8mask, int cs, int vom, int vshin, int cshift, int bs, int ept8)
{
    int t, rem; swz_t(blockIdx.x, bs, t, rem);
    int il = rem*256 + threadIdx.x;
    int c8 = il & c8mask;
    int r  = (il >> cs) & vom;
    size_t i = (size_t)t * ept8 + il;
    const bf16* xt = xin + ((size_t)t << (vshin + cshift));
    int r3 = 3*r;
    int j0 = col[r3], j1 = col[r3+1], j2 = col[r3+2];
    float v0 = val[r3], v1 = val[r3+1], v2 = val[r3+2];
    int c = c8 << 3;
    short8v a = *(const short8v*)&xt[((size_t)j0 << cshift) + c];
    short8v b = *(const short8v*)&xt[((size_t)j1 << cshift) + c];
    short8v d = *(const short8v*)&xt[((size_t)j2 << cshift) + c];
    short8v o;
    #pragma unroll
    for (int q = 0; q < 8; q++)
        o[q] = f2bs(v0*bsu2f(a[q]) + v1*bsu2f(b[q]) + v2*bsu2f(d[q]));
    *(short8v*)&out[i << 3] = o;
}

// ---------- pipelined MFMA(32x32x16) spiral conv + ELU ----------
// Register-prefetch double buffer: chunk ch+1's global loads are issued into
// VGPRs before chunk ch's compute, committed to LDS after the barrier.
// A frag: m=lane&31, k=half*8+j ; B frag: n=lane&31. C/D: col=lane&31,
// row=(reg&3)+8*(reg>>2)+4*half  [verified m74/m101, rounds 8-11]
template<int KTOT, int CSHIFT, int NTOT, int MTILES, typename TOUT>
__global__ __launch_bounds__(256) void k_conv_p(
    const bf16* __restrict__ xin, const int* __restrict__ spiral,
    const short* __restrict__ wt, const float* __restrict__ bias, TOUT* __restrict__ out,
    int vshift, int bs, int nbshift)
{
    constexpr int MT   = 128*MTILES;
    constexpr int NCH  = KTOT >> 6;
    constexpr int CSUB = CSHIFT - 6;
    constexpr int AU   = MT*8/256;     // A prefetch regs per thread
    __shared__ short lds_a[MT*72];
    __shared__ short lds_b[32*72];
    const int tid = threadIdx.x;
    const int lane = tid & 63;
    const int wv = tid >> 6;
    const int col = lane & 31;
    const int half = lane >> 5;

    int t, rem; swz_t(blockIdx.x, bs, t, rem);
    const int nb = rem & ((1 << nbshift) - 1);
    const int vt = rem >> nbshift;
    const int mbase = vt*MT;
    const size_t xslab = (size_t)t << (vshift + CSHIFT);

    short8v pa[AU];
    short8v pb;
    const int am = tid >> 3;               // A row handled by this thread (base)
    const int ak = (tid & 7) << 3;         // A k-offset within chunk
    const int bn = tid >> 3;               // B row
    const int bk = (tid & 7) << 3;

    auto issue = [&](int ch){
        int s = ch >> CSUB;
        int coff = ((ch & ((1 << CSUB) - 1)) << 6) + ak;
        #pragma unroll
        for (int u = 0; u < AU; u++){
            int j = spiral[(mbase + am + u*32)*9 + s];
            pa[u] = *(const short8v*)&xin[xslab + ((size_t)j << CSHIFT) + coff];
        }
        pb = *(const short8v*)&wt[(size_t)(nb*32 + bn)*KTOT + (ch << 6) + bk];
    };
    auto commit = [&](){
        #pragma unroll
        for (int u = 0; u < AU; u++)
            *(short8v*)&lds_a[(am + u*32)*72 + ak] = pa[u];
        *(short8v*)&lds_b[bn*72 + bk] = pb;
    };

    f32x16 acc[MTILES];
    {
        float bv = bias[nb*32 + col];
        #pragma unroll
        for (int h = 0; h < MTILES; h++)
            #pragma unroll
            for (int r = 0; r < 16; r++) acc[h][r] = bv;
    }

    issue(0);
    commit();
    __syncthreads();
    for (int ch = 0; ch < NCH; ch++){
        if (ch + 1 < NCH) issue(ch + 1);   // loads in flight during compute
        #pragma unroll
        for (int ks = 0; ks < 4; ks++){
            short8v b = *(short8v*)&lds_b[col*72 + ks*16 + half*8];
            #pragma unroll
            for (int h = 0; h < MTILES; h++){
                short8v a = *(short8v*)&lds_a[(h*128 + wv*32 + col)*72 + ks*16 + half*8];
                acc[h] = __builtin_amdgcn_mfma_f32_32x32x16_bf16(a, b, acc[h], 0, 0, 0);
            }
        }
        __syncthreads();                   // all waves done reading LDS
        if (ch + 1 < NCH){
            commit();                      // vmcnt wait lands here, after compute
            __syncthreads();
        }
    }
    // epilogue
    #pragma unroll
    for (int h = 0; h < MTILES; h++){
        size_t mb = ((size_t)t << vshift) + mbase + h*128 + wv*32;
        #pragma unroll
        for (int r = 0; r < 16; r++){
            int row = (r & 3) + 8*(r >> 2) + 4*half;
            float vv = acc[h][r];
            vv = vv > 0.f ? vv : __expf(vv) - 1.f;
            sto(&out[(mb + row)*NTOT + nb*32 + col], vv);
        }
    }
}

// ---------- VALU spiral conv (encoder; tiny) ----------
template<typename TIN>
__global__ __launch_bounds__(256) void k_conv(const TIN* __restrict__ xin,
    const int* __restrict__ spiral, const float* __restrict__ w, const float* __restrict__ bias,
    float* __restrict__ out, int TV, int V, int vshift, int C, int O2, int o2shift,
    int K, int KP, int MT)
{
    extern __shared__ float lds[];
    const int S = 9;
    int tid = threadIdx.x;
    int O = O2 << 1;
    int gmbase = blockIdx.x * MT;

    int total = MT * K;
    for (int e = tid; e < total; e += 256){
        int m = e / K, k = e - m*K;
        int gm = gmbase + m;
        if (gm < TV){
            int t = gm >> vshift, v = gm & (V-1);
            int s = k / C, c = k - s*C;
            int jj = spiral[v*S + s];
            lds[m*KP + k] = tof(xin[((size_t)t*V + jj)*C + c]);
        }
    }
    __syncthreads();

    int m = tid >> o2shift;
    int o = tid & (O2 - 1);
    int gm = gmbase + m;
    if (gm >= TV) return;
    const float* g  = lds + m*KP;
    const float* wp = w + 2*o;
    float acc0 = bias[2*o];
    float acc1 = bias[2*o+1];
    int K4 = K & ~3;
    for (int k = 0; k < K4; k += 4){
        float4 g4 = *(const float4*)(g + k);
        float2 w0 = *(const float2*)(wp + (size_t)k    *O);
        float2 w1 = *(const float2*)(wp + (size_t)(k+1)*O);
        float2 w2 = *(const float2*)(wp + (size_t)(k+2)*O);
        float2 w3 = *(const float2*)(wp + (size_t)(k+3)*O);
        acc0 += g4.x*w0.x + g4.y*w1.x + g4.z*w2.x + g4.w*w3.x;
        acc1 += g4.x*w0.y + g4.y*w1.y + g4.z*w2.y + g4.w*w3.y;
    }
    for (int k = K4; k < K; k++){
        float gv = g[k];
        acc0 += gv * wp[(size_t)k*O];
        acc1 += gv * wp[(size_t)k*O + 1];
    }
    acc0 = acc0 > 0.f ? acc0 : __expf(acc0) - 1.f;
    acc1 = acc1 > 0.f ? acc1 : __expf(acc1) - 1.f;
    float2 r; r.x = acc0; r.y = acc1;
    *(float2*)(out + (size_t)gm*O + 2*o) = r;
}

// ---------- final conv (O=3, no ELU) + actor residual; bf16 input, 16-B gather ----------
__global__ __launch_bounds__(256) void k_outconv(const bf16* __restrict__ xin,
    const int* __restrict__ spiral, const float* __restrict__ w, const float* __restrict__ bias,
    const float* __restrict__ actor, float* __restrict__ out, int vshift, int bs)
{
    int t, rem; swz_t(blockIdx.x, bs, t, rem);
    int v = rem*256 + threadIdx.x;
    size_t i = ((size_t)t << vshift) + v;
    const bf16* xt = xin + (((size_t)t << vshift)) * 32;
    float a0 = bias[0], a1 = bias[1], a2 = bias[2];
    #pragma unroll
    for (int s = 0; s < 9; s++){
        int j = spiral[v*9 + s];
        const short8v* xr = (const short8v*)(xt + (size_t)j*32);
        #pragma unroll
        for (int h = 0; h < 4; h++){
            short8v sv = xr[h];
            const float* wr = w + (s*32 + h*8)*3;
            #pragma unroll
            for (int q = 0; q < 8; q++){
                float xv = bsu2f(sv[q]);
                a0 += xv * wr[q*3];
                a1 += xv * wr[q*3+1];
                a2 += xv * wr[q*3+2];
            }
        }
    }
    a0 += actor[v*3]; a1 += actor[v*3+1]; a2 += actor[v*3+2];
    out[i*3]   = a0;
    out[i*3+1] = a1;
    out[i*3+2] = a2;
}

extern "C" void kernel_launch(void* const* d_in, const int* in_sizes, int n_in,
                              void* d_out, int out_size, void* d_ws, size_t ws_size,
                              hipStream_t stream)
{
    (void)n_in; (void)out_size; (void)ws_size;
    const float* hs        = (const float*)d_in[0];
    const float* actor     = (const float*)d_in[1];
    const float* audio_w   = (const float*)d_in[2];
    const float* audio_b   = (const float*)d_in[3];
    const float* enc_w[4]  = {(const float*)d_in[4],(const float*)d_in[6],(const float*)d_in[8],(const float*)d_in[10]};
    const float* enc_b[4]  = {(const float*)d_in[5],(const float*)d_in[7],(const float*)d_in[9],(const float*)d_in[11]};
    const float* enc_lat_w = (const float*)d_in[12];
    const float* enc_lat_b = (const float*)d_in[13];
    const float* dec_lin_w = (const float*)d_in[14];
    const float* dec_lin_b = (const float*)d_in[15];
    const float* dec_w[4]  = {(const float*)d_in[16],(const float*)d_in[18],(const float*)d_in[20],(const float*)d_in[22]};
    const float* dec_b[4]  = {(const float*)d_in[17],(const float*)d_in[19],(const float*)d_in[21],(const float*)d_in[23]};
    const float* dec_out_w = (const float*)d_in[24];
    const float* dec_out_b = (const float*)d_in[25];
    const int*   spiral[4] = {(const int*)d_in[26],(const int*)d_in[27],(const int*)d_in[28],(const int*)d_in[29]};

    const int* dcol[4]; const float* dval[4]; const int* ucol[4]; const float* uval[4];
    bool interleaved = (in_sizes[33] == 3*8192);
    for (int i = 0; i < 4; i++){
        if (interleaved){
            int b = 30 + 6*i;
            dcol[i] = (const int*)d_in[b+1]; dval[i] = (const float*)d_in[b+2];
            ucol[i] = (const int*)d_in[b+4]; uval[i] = (const float*)d_in[b+5];
        } else {
            dcol[i] = (const int*)d_in[31+3*i]; dval[i] = (const float*)d_in[32+3*i];
            ucol[i] = (const int*)d_in[43+3*i]; uval[i] = (const float*)d_in[44+3*i];
        }
    }

    // ---- workspace ----
    char* ws = (char*)d_ws;
    size_t off = 0;
    auto alloc = [&](size_t bytes)->char* {
        char* p = ws + off; off += (bytes + 255) & ~(size_t)255; return p;
    };
    float* encX0 = (float*)alloc((size_t)262144*4);
    float* encP0 = (float*)alloc((size_t)65536*4);
    float* encX1 = (float*)alloc((size_t)131072*4);
    float* encP1 = (float*)alloc((size_t)32768*4);
    float* encX2 = (float*)alloc((size_t)32768*4);
    float* encP2 = (float*)alloc((size_t)8192*4);
    float* encX3 = (float*)alloc((size_t)16384*4);
    float* encP3 = (float*)alloc((size_t)4096*4);
    float* aemb  = (float*)alloc((size_t)4096*4);
    float* pemb  = (float*)alloc((size_t)64*4);
    short* wt0   = (short*)alloc((size_t)147456*2);   // dec0 [128][1152]
    short* wt1   = (short*)alloc((size_t)73728*2);    // dec1 [64][1152]
    short* wt2   = (short*)alloc((size_t)36864*2);    // dec2 [64][576]
    short* wt3   = (short*)alloc((size_t)18432*2);    // dec3 [32][576]
    bf16*  Pb    = (bf16*)alloc((size_t)36*1048576);  // conv/declin outputs
    bf16*  Qb    = (bf16*)alloc((size_t)68*1048576);  // pool outputs

    // ---- prep (fused; 1080 transpose blocks + 64 audio blocks) ----
    k_prep<<<1144,256,0,stream>>>(dec_w[0], dec_w[1], dec_w[2], dec_w[3],
                                  wt0, wt1, wt2, wt3, hs, audio_w, audio_b, aemb);

    // ---- encoder (VALU; tiny, B=1) ----
    k_conv<float><<<512,256, 16*28*4, stream>>>(actor, spiral[0], enc_w[0], enc_b[0], encX0, 8192, 8192,13,   3,16,4,  27,  28,16);
    k_pool4<<<64,256,0,stream>>>(encX0, dcol[0], dval[0], encP0, 16384, 7,3, 2047,11, 8192);
    k_conv<float><<<256,256, 8*292*4, stream>>>(encP0, spiral[1], enc_w[1], enc_b[1], encX1, 2048, 2048,11,  32,32,5, 288, 292, 8);
    k_pool4<<<32,256,0,stream>>>(encX1, dcol[1], dval[1], encP1, 8192, 15,4, 511,9, 2048);
    k_conv<float><<<64,256, 8*580*4, stream>>>(encP1, spiral[2], enc_w[2], enc_b[2], encX2, 512, 512,9,  64,32,5, 576, 580, 8);
    k_pool4<<<8,256,0,stream>>>(encX2, dcol[2], dval[2], encP2, 2048, 15,4, 127,7, 512);
    k_conv<float><<<32,256, 4*580*4, stream>>>(encP2, spiral[3], enc_w[3], enc_b[3], encX3, 128, 128,7,  64,64,6, 576, 580, 4);
    k_pool4<<<4,256,0,stream>>>(encX3, dcol[3], dval[3], encP3, 1024, 31,5, 31,5, 128);
    k_enclat<<<64,256,0,stream>>>(encP3, enc_lat_w, enc_lat_b, pemb);

    // ---- decoder (XCD t-swizzled, all-bf16, pipelined convs) ----
    k_declin4<<<dim3(4,64),256,0,stream>>>(aemb, pemb, dec_lin_w, dec_lin_b, Pb);           // ->[64][32][128] bf16

    k_poolb<<<512,256,0,stream>>>(Pb, ucol[3], uval[3], Qb, 15,4, 127, 5,7, 3, 2048);        // ->[64][128][128]
    k_conv_p<1152,7,128,1,bf16><<<256,256,0,stream>>>(Qb, spiral[3], wt0, dec_b[0], Pb, 7, 2, 2);   // ->[64][128][128]

    k_poolb<<<2048,256,0,stream>>>(Pb, ucol[2], uval[2], Qb, 15,4, 511, 7,7, 5, 8192);       // ->[64][512][128]
    k_conv_p<1152,7,64,2,bf16><<<256,256,0,stream>>>(Qb, spiral[2], wt1, dec_b[1], Pb, 9, 2, 1);    // ->[64][512][64]

    k_poolb<<<4096,256,0,stream>>>(Pb, ucol[1], uval[1], Qb, 7,3, 2047, 9,6, 6, 16384);      // ->[64][2048][64]
    k_conv_p<576,6,64,2,bf16><<<1024,256,0,stream>>>(Qb, spiral[1], wt2, dec_b[2], Pb, 11, 4, 1);   // ->[64][2048][64]

    k_poolb<<<16384,256,0,stream>>>(Pb, ucol[0], uval[0], Qb, 7,3, 8191, 11,6, 8, 65536);    // ->[64][8192][64]
    k_conv_p<576,6,32,2,bf16><<<2048,256,0,stream>>>(Qb, spiral[0], wt3, dec_b[3], Pb, 13, 5, 0);   // ->[64][8192][32]

    k_outconv<<<2048,256,0,stream>>>(Pb, spiral[0], dec_out_w, dec_out_b, actor, (float*)d_out, 13, 5);
}

// Round 13
// 462.574 us; speedup vs baseline: 1.3263x; 1.0520x over previous
//
#include <hip/hip_runtime.h>
#include <hip/hip_bf16.h>

typedef __hip_bfloat16 bf16;
typedef __attribute__((ext_vector_type(8))) short short8v;
typedef __attribute__((ext_vector_type(16))) float f32x16;

__device__ __forceinline__ float tof(float v){ return v; }
__device__ __forceinline__ float tof(bf16 v){ return __bfloat162float(v); }
__device__ __forceinline__ void sto(float* p, float v){ *p = v; }
__device__ __forceinline__ void sto(bf16* p, float v){ *p = __float2bfloat16(v); }
__device__ __forceinline__ short f2bs(float f){ bf16 h = __float2bfloat16(f); return *(short*)&h; }
__device__ __forceinline__ float bsu2f(short s){
    return __uint_as_float(((unsigned)(unsigned short)s) << 16);
}

__device__ __forceinline__ void sto4(float* p, float4 v){ *(float4*)p = v; }
__device__ __forceinline__ void sto4(bf16* p, float4 v){
    short4 s; s.x=f2bs(v.x); s.y=f2bs(v.y); s.z=f2bs(v.z); s.w=f2bs(v.w);
    *(short4*)p = s;
}

// XCD-aware swizzle for 64-frame (t) problems: grid = 64 << bs blocks.
__device__ __forceinline__ void swz_t(int b, int bs, int& t, int& rem){
    int x = b & 7, k = b >> 3;
    t = x*8 + (k >> bs);
    rem = k & ((1 << bs) - 1);
}

// ---------- fused prep: 4 decoder transposes + outconv padded transpose
// + audio embedding (block-per-t, 4x64 LDS reduce) ----------
__global__ __launch_bounds__(256) void k_prep(
    const float* __restrict__ w0, const float* __restrict__ w1,
    const float* __restrict__ w2, const float* __restrict__ w3,
    const float* __restrict__ w4,
    short* __restrict__ wt0, short* __restrict__ wt1,
    short* __restrict__ wt2, short* __restrict__ wt3,
    short* __restrict__ wt4,
    const float* __restrict__ hs, const float* __restrict__ aw,
    const float* __restrict__ ab, float* __restrict__ aemb)
{
    __shared__ float red[4][64];
    int b = blockIdx.x, tid = threadIdx.x;
    if (b < 1080){
        // i indexes the SOURCE (contiguous): coalesced read, scattered 2-B write.
        const float* w; short* wt; int K, nsh, i;
        if      (b < 576) { w = w0; wt = wt0; K = 1152; nsh = 7; i = b*256 + tid; }
        else if (b < 864) { w = w1; wt = wt1; K = 1152; nsh = 6; i = (b-576)*256 + tid; }
        else if (b < 1008){ w = w2; wt = wt2; K = 576;  nsh = 6; i = (b-864)*256 + tid; }
        else              { w = w3; wt = wt3; K = 576;  nsh = 5; i = (b-1008)*256 + tid; }
        int k = i >> nsh, n = i & ((1 << nsh) - 1);
        wt[n*K + k] = f2bs(w[i]);
    } else if (b < 1116){
        // wt4[32][288]: rows 0..2 = dec_out_w^T, rows 3..31 = 0
        int i = (b - 1080)*256 + tid;    // 0..9215
        int k = i >> 5, n = i & 31;
        wt4[n*288 + k] = (n < 3) ? f2bs(w4[k*3 + n]) : (short)0;
    } else {
        int t = b - 1116;                // 0..63
        int kg = tid >> 6, l = tid & 63;
        const float* h = hs + t*768;
        float acc = 0.f;
        int k0 = kg*192;
        #pragma unroll 8
        for (int k = k0; k < k0 + 192; k++) acc += h[k] * aw[k*64 + l];
        red[kg][l] = acc;
        __syncthreads();
        if (kg == 0)
            aemb[t*64 + l] = red[0][l] + red[1][l] + red[2][l] + red[3][l] + ab[l];
    }
}

// ---------- enc_lat ----------
__global__ __launch_bounds__(256) void k_enclat(const float* __restrict__ flat,
    const float* __restrict__ w, const float* __restrict__ b, float* __restrict__ out)
{
    __shared__ float red[256];
    int l = blockIdx.x, tid = threadIdx.x;
    float acc = 0.f;
    for (int k = tid; k < 4096; k += 256) acc += flat[k] * w[k*64 + l];
    red[tid] = acc; __syncthreads();
    for (int s = 128; s > 0; s >>= 1){ if (tid < s) red[tid] += red[tid+s]; __syncthreads(); }
    if (tid == 0) out[l] = red[0] + b[l];
}

// ---------- dec_lin fused with latent concat; bf16 out [t][32][128] ----------
__global__ __launch_bounds__(256) void k_declin4(const float* __restrict__ ae,
    const float* __restrict__ pe, const float* __restrict__ w, const float* __restrict__ b,
    bf16* __restrict__ out)
{
    int n4 = blockIdx.x*256 + threadIdx.x;   // 0..1023
    int t = blockIdx.y;
    float4 acc = *(const float4*)&b[n4*4];
    const float* a = ae + t*64;
    #pragma unroll 4
    for (int k = 0; k < 64; k++){
        float av = a[k];
        float4 wv = *(const float4*)&w[(size_t)k*4096 + n4*4];
        acc.x += av*wv.x; acc.y += av*wv.y; acc.z += av*wv.z; acc.w += av*wv.w;
    }
    #pragma unroll 4
    for (int k = 0; k < 64; k++){
        float pv = pe[k];
        float4 wv = *(const float4*)&w[(size_t)(64+k)*4096 + n4*4];
        acc.x += pv*wv.x; acc.y += pv*wv.y; acc.z += pv*wv.z; acc.w += pv*wv.w;
    }
    sto4(&out[(size_t)t*4096 + n4*4], acc);
}

// ---------- encoder 3-tap pool, f32, 4 ch/thread ----------
__global__ __launch_bounds__(256) void k_pool4(const float* __restrict__ xin,
    const int* __restrict__ col, const float* __restrict__ val, float* __restrict__ out,
    int total4, int c4mask, int cs, int vomask, int vos, int Vi)
{
    int i = blockIdx.x*256 + threadIdx.x;
    if (i >= total4) return;
    int c4 = i & c4mask;
    int rv = i >> cs;
    int r  = rv & vomask;
    int t  = rv >> vos;
    int C  = (c4mask + 1) << 2;
    const float* xt = xin + (size_t)t * Vi * C;
    int r3 = 3*r;
    int j0 = col[r3], j1 = col[r3+1], j2 = col[r3+2];
    float v0 = val[r3], v1 = val[r3+1], v2 = val[r3+2];
    int c = c4 << 2;
    float4 a = *(const float4*)&xt[(size_t)j0*C + c];
    float4 b = *(const float4*)&xt[(size_t)j1*C + c];
    float4 d = *(const float4*)&xt[(size_t)j2*C + c];
    float4 o;
    o.x = v0*a.x + v1*b.x + v2*d.x;
    o.y = v0*a.y + v1*b.y + v2*d.y;
    o.z = v0*a.z + v1*b.z + v2*d.z;
    o.w = v0*a.w + v1*b.w + v2*d.w;
    sto4(&out[(size_t)i << 2], o);
}

// ---------- decoder 3-tap pool, bf16 in/out, 8 ch/thread, t-swizzled ----------
__global__ __launch_bounds__(256) void k_poolb(const bf16* __restrict__ xin,
    const int* __restrict__ col, const float* __restrict__ val, bf16* __restrict__ out,
    int c8mask, int cs, int vom, int vshin, int cshift, int bs, int ept8)
{
    int t, rem; swz_t(blockIdx.x, bs, t, rem);
    int il = rem*256 + threadIdx.x;
    int c8 = il & c8mask;
    int r  = (il >> cs) & vom;
    size_t i = (size_t)t * ept8 + il;
    const bf16* xt = xin + ((size_t)t << (vshin + cshift));
    int r3 = 3*r;
    int j0 = col[r3], j1 = col[r3+1], j2 = col[r3+2];
    float v0 = val[r3], v1 = val[r3+1], v2 = val[r3+2];
    int c = c8 << 3;
    short8v a = *(const short8v*)&xt[((size_t)j0 << cshift) + c];
    short8v b = *(const short8v*)&xt[((size_t)j1 << cshift) + c];
    short8v d = *(const short8v*)&xt[((size_t)j2 << cshift) + c];
    short8v o;
    #pragma unroll
    for (int q = 0; q < 8; q++)
        o[q] = f2bs(v0*bsu2f(a[q]) + v1*bsu2f(b[q]) + v2*bsu2f(d[q]));
    *(short8v*)&out[i << 3] = o;
}

// ---------- pipelined MFMA(32x32x16) spiral conv + ELU ----------
// Register-prefetch double buffer (rounds 8-12 verified layouts).
template<int KTOT, int CSHIFT, int NTOT, int MTILES, typename TOUT>
__global__ __launch_bounds__(256) void k_conv_p(
    const bf16* __restrict__ xin, const int* __restrict__ spiral,
    const short* __restrict__ wt, const float* __restrict__ bias, TOUT* __restrict__ out,
    int vshift, int bs, int nbshift)
{
    constexpr int MT   = 128*MTILES;
    constexpr int NCH  = KTOT >> 6;
    constexpr int CSUB = CSHIFT - 6;
    constexpr int AU   = MT*8/256;     // A prefetch regs per thread
    __shared__ short lds_a[MT*72];
    __shared__ short lds_b[32*72];
    const int tid = threadIdx.x;
    const int lane = tid & 63;
    const int wv = tid >> 6;
    const int col = lane & 31;
    const int half = lane >> 5;

    int t, rem; swz_t(blockIdx.x, bs, t, rem);
    const int nb = rem & ((1 << nbshift) - 1);
    const int vt = rem >> nbshift;
    const int mbase = vt*MT;
    const size_t xslab = (size_t)t << (vshift + CSHIFT);

    short8v pa[AU];
    short8v pb;
    const int am = tid >> 3;
    const int ak = (tid & 7) << 3;
    const int bn = tid >> 3;
    const int bk = (tid & 7) << 3;

    auto issue = [&](int ch){
        int s = ch >> CSUB;
        int coff = ((ch & ((1 << CSUB) - 1)) << 6) + ak;
        #pragma unroll
        for (int u = 0; u < AU; u++){
            int j = spiral[(mbase + am + u*32)*9 + s];
            pa[u] = *(const short8v*)&xin[xslab + ((size_t)j << CSHIFT) + coff];
        }
        pb = *(const short8v*)&wt[(size_t)(nb*32 + bn)*KTOT + (ch << 6) + bk];
    };
    auto commit = [&](){
        #pragma unroll
        for (int u = 0; u < AU; u++)
            *(short8v*)&lds_a[(am + u*32)*72 + ak] = pa[u];
        *(short8v*)&lds_b[bn*72 + bk] = pb;
    };

    f32x16 acc[MTILES];
    {
        float bv = bias[nb*32 + col];
        #pragma unroll
        for (int h = 0; h < MTILES; h++)
            #pragma unroll
            for (int r = 0; r < 16; r++) acc[h][r] = bv;
    }

    issue(0);
    commit();
    __syncthreads();
    for (int ch = 0; ch < NCH; ch++){
        if (ch + 1 < NCH) issue(ch + 1);
        #pragma unroll
        for (int ks = 0; ks < 4; ks++){
            short8v b = *(short8v*)&lds_b[col*72 + ks*16 + half*8];
            #pragma unroll
            for (int h = 0; h < MTILES; h++){
                short8v a = *(short8v*)&lds_a[(h*128 + wv*32 + col)*72 + ks*16 + half*8];
                acc[h] = __builtin_amdgcn_mfma_f32_32x32x16_bf16(a, b, acc[h], 0, 0, 0);
            }
        }
        __syncthreads();
        if (ch + 1 < NCH){
            commit();
            __syncthreads();
        }
    }
    #pragma unroll
    for (int h = 0; h < MTILES; h++){
        size_t mb = ((size_t)t << vshift) + mbase + h*128 + wv*32;
        #pragma unroll
        for (int r = 0; r < 16; r++){
            int row = (r & 3) + 8*(r >> 2) + 4*half;
            float vv = acc[h][r];
            vv = vv > 0.f ? vv : __expf(vv) - 1.f;
            sto(&out[(mb + row)*NTOT + nb*32 + col], vv);
        }
    }
}

// ---------- final conv as pipelined MFMA GEMM (N=3 padded to 32) + actor ----------
// M-tile 256, K=288 in 9 chunks of 32 (= one spiral step), 4 lanes per 64-B row
// during staging (16 lines/wave-load). No ELU; f32 out; actor residual.
__global__ __launch_bounds__(256) void k_outmfma(
    const bf16* __restrict__ xin, const int* __restrict__ spiral,
    const short* __restrict__ wt, const float* __restrict__ bias,
    const float* __restrict__ actor, float* __restrict__ out)
{
    __shared__ short lds_a[256*36];
    __shared__ short lds_b[32*36];
    const int tid = threadIdx.x;
    const int lane = tid & 63;
    const int wv = tid >> 6;
    const int col = lane & 31;
    const int half = lane >> 5;

    int t, rem; swz_t(blockIdx.x, 5, t, rem);     // grid = 2048 = 64<<5
    const int mbase = rem*256;
    const size_t xslab = (size_t)t << 18;         // 8192 rows * 32 ch

    short8v pa[4];
    short8v pb;
    const int am = tid >> 2;          // 0..63
    const int ak = (tid & 3) << 3;    // short offset in 32-short row

    auto issue = [&](int s){
        #pragma unroll
        for (int u = 0; u < 4; u++){
            int j = spiral[(mbase + am + u*64)*9 + s];
            pa[u] = *(const short8v*)&xin[xslab + ((size_t)j << 5) + ak];
        }
        if (tid < 128)
            pb = *(const short8v*)&wt[am*288 + s*32 + ak];
    };
    auto commit = [&](){
        #pragma unroll
        for (int u = 0; u < 4; u++)
            *(short8v*)&lds_a[(am + u*64)*36 + ak] = pa[u];
        if (tid < 128)
            *(short8v*)&lds_b[am*36 + ak] = pb;
    };

    f32x16 acc[2];
    {
        float bv = (col < 3) ? bias[col] : 0.f;
        #pragma unroll
        for (int h = 0; h < 2; h++)
            #pragma unroll
            for (int r = 0; r < 16; r++) acc[h][r] = bv;
    }

    issue(0); commit(); __syncthreads();
    for (int s = 0; s < 9; s++){
        if (s + 1 < 9) issue(s + 1);
        #pragma unroll
        for (int ks = 0; ks < 2; ks++){
            short8v b = *(short8v*)&lds_b[col*36 + ks*16 + half*8];
            #pragma unroll
            for (int h = 0; h < 2; h++){
                short8v a = *(short8v*)&lds_a[(h*128 + wv*32 + col)*36 + ks*16 + half*8];
                acc[h] = __builtin_amdgcn_mfma_f32_32x32x16_bf16(a, b, acc[h], 0, 0, 0);
            }
        }
        __syncthreads();
        if (s + 1 < 9){ commit(); __syncthreads(); }
    }
    if (col < 3){
        #pragma unroll
        for (int h = 0; h < 2; h++){
            int rowb = mbase + h*128 + wv*32;
            #pragma unroll
            for (int r = 0; r < 16; r++){
                int row = rowb + (r & 3) + 8*(r >> 2) + 4*half;
                out[(((size_t)t << 13) + row)*3 + col] = acc[h][r] + actor[row*3 + col];
            }
        }
    }
}

// ---------- VALU spiral conv (encoder; tiny) ----------
template<typename TIN>
__global__ __launch_bounds__(256) void k_conv(const TIN* __restrict__ xin,
    const int* __restrict__ spiral, const float* __restrict__ w, const float* __restrict__ bias,
    float* __restrict__ out, int TV, int V, int vshift, int C, int O2, int o2shift,
    int K, int KP, int MT)
{
    extern __shared__ float lds[];
    const int S = 9;
    int tid = threadIdx.x;
    int O = O2 << 1;
    int gmbase = blockIdx.x * MT;

    int total = MT * K;
    for (int e = tid; e < total; e += 256){
        int m = e / K, k = e - m*K;
        int gm = gmbase + m;
        if (gm < TV){
            int t = gm >> vshift, v = gm & (V-1);
            int s = k / C, c = k - s*C;
            int jj = spiral[v*S + s];
            lds[m*KP + k] = tof(xin[((size_t)t*V + jj)*C + c]);
        }
    }
    __syncthreads();

    int m = tid >> o2shift;
    int o = tid & (O2 - 1);
    int gm = gmbase + m;
    if (gm >= TV) return;
    const float* g  = lds + m*KP;
    const float* wp = w + 2*o;
    float acc0 = bias[2*o];
    float acc1 = bias[2*o+1];
    int K4 = K & ~3;
    for (int k = 0; k < K4; k += 4){
        float4 g4 = *(const float4*)(g + k);
        float2 w0 = *(const float2*)(wp + (size_t)k    *O);
        float2 w1 = *(const float2*)(wp + (size_t)(k+1)*O);
        float2 w2 = *(const float2*)(wp + (size_t)(k+2)*O);
        float2 w3 = *(const float2*)(wp + (size_t)(k+3)*O);
        acc0 += g4.x*w0.x + g4.y*w1.x + g4.z*w2.x + g4.w*w3.x;
        acc1 += g4.x*w0.y + g4.y*w1.y + g4.z*w2.y + g4.w*w3.y;
    }
    for (int k = K4; k < K; k++){
        float gv = g[k];
        acc0 += gv * wp[(size_t)k*O];
        acc1 += gv * wp[(size_t)k*O + 1];
    }
    acc0 = acc0 > 0.f ? acc0 : __expf(acc0) - 1.f;
    acc1 = acc1 > 0.f ? acc1 : __expf(acc1) - 1.f;
    float2 r; r.x = acc0; r.y = acc1;
    *(float2*)(out + (size_t)gm*O + 2*o) = r;
}

extern "C" void kernel_launch(void* const* d_in, const int* in_sizes, int n_in,
                              void* d_out, int out_size, void* d_ws, size_t ws_size,
                              hipStream_t stream)
{
    (void)n_in; (void)out_size; (void)ws_size;
    const float* hs        = (const float*)d_in[0];
    const float* actor     = (const float*)d_in[1];
    const float* audio_w   = (const float*)d_in[2];
    const float* audio_b   = (const float*)d_in[3];
    const float* enc_w[4]  = {(const float*)d_in[4],(const float*)d_in[6],(const float*)d_in[8],(const float*)d_in[10]};
    const float* enc_b[4]  = {(const float*)d_in[5],(const float*)d_in[7],(const float*)d_in[9],(const float*)d_in[11]};
    const float* enc_lat_w = (const float*)d_in[12];
    const float* enc_lat_b = (const float*)d_in[13];
    const float* dec_lin_w = (const float*)d_in[14];
    const float* dec_lin_b = (const float*)d_in[15];
    const float* dec_w[4]  = {(const float*)d_in[16],(const float*)d_in[18],(const float*)d_in[20],(const float*)d_in[22]};
    const float* dec_b[4]  = {(const float*)d_in[17],(const float*)d_in[19],(const float*)d_in[21],(const float*)d_in[23]};
    const float* dec_out_w = (const float*)d_in[24];
    const float* dec_out_b = (const float*)d_in[25];
    const int*   spiral[4] = {(const int*)d_in[26],(const int*)d_in[27],(const int*)d_in[28],(const int*)d_in[29]};

    const int* dcol[4]; const float* dval[4]; const int* ucol[4]; const float* uval[4];
    bool interleaved = (in_sizes[33] == 3*8192);
    for (int i = 0; i < 4; i++){
        if (interleaved){
            int b = 30 + 6*i;
            dcol[i] = (const int*)d_in[b+1]; dval[i] = (const float*)d_in[b+2];
            ucol[i] = (const int*)d_in[b+4]; uval[i] = (const float*)d_in[b+5];
        } else {
            dcol[i] = (const int*)d_in[31+3*i]; dval[i] = (const float*)d_in[32+3*i];
            ucol[i] = (const int*)d_in[43+3*i]; uval[i] = (const float*)d_in[44+3*i];
        }
    }

    // ---- workspace ----
    char* ws = (char*)d_ws;
    size_t off = 0;
    auto alloc = [&](size_t bytes)->char* {
        char* p = ws + off; off += (bytes + 255) & ~(size_t)255; return p;
    };
    float* encX0 = (float*)alloc((size_t)262144*4);
    float* encP0 = (float*)alloc((size_t)65536*4);
    float* encX1 = (float*)alloc((size_t)131072*4);
    float* encP1 = (float*)alloc((size_t)32768*4);
    float* encX2 = (float*)alloc((size_t)32768*4);
    float* encP2 = (float*)alloc((size_t)8192*4);
    float* encX3 = (float*)alloc((size_t)16384*4);
    float* encP3 = (float*)alloc((size_t)4096*4);
    float* aemb  = (float*)alloc((size_t)4096*4);
    float* pemb  = (float*)alloc((size_t)64*4);
    short* wt0   = (short*)alloc((size_t)147456*2);   // dec0 [128][1152]
    short* wt1   = (short*)alloc((size_t)73728*2);    // dec1 [64][1152]
    short* wt2   = (short*)alloc((size_t)36864*2);    // dec2 [64][576]
    short* wt3   = (short*)alloc((size_t)18432*2);    // dec3 [32][576]
    short* wt4   = (short*)alloc((size_t)9216*2);     // out  [32pad][288]
    bf16*  Pb    = (bf16*)alloc((size_t)36*1048576);  // conv/declin outputs
    bf16*  Qb    = (bf16*)alloc((size_t)68*1048576);  // pool outputs

    // ---- prep (fused; 1080 transposes + 36 wt4 + 64 audio) ----
    k_prep<<<1180,256,0,stream>>>(dec_w[0], dec_w[1], dec_w[2], dec_w[3], dec_out_w,
                                  wt0, wt1, wt2, wt3, wt4, hs, audio_w, audio_b, aemb);

    // ---- encoder (VALU; tiny, B=1) ----
    k_conv<float><<<512,256, 16*28*4, stream>>>(actor, spiral[0], enc_w[0], enc_b[0], encX0, 8192, 8192,13,   3,16,4,  27,  28,16);
    k_pool4<<<64,256,0,stream>>>(encX0, dcol[0], dval[0], encP0, 16384, 7,3, 2047,11, 8192);
    k_conv<float><<<256,256, 8*292*4, stream>>>(encP0, spiral[1], enc_w[1], enc_b[1], encX1, 2048, 2048,11,  32,32,5, 288, 292, 8);
    k_pool4<<<32,256,0,stream>>>(encX1, dcol[1], dval[1], encP1, 8192, 15,4, 511,9, 2048);
    k_conv<float><<<64,256, 8*580*4, stream>>>(encP1, spiral[2], enc_w[2], enc_b[2], encX2, 512, 512,9,  64,32,5, 576, 580, 8);
    k_pool4<<<8,256,0,stream>>>(encX2, dcol[2], dval[2], encP2, 2048, 15,4, 127,7, 512);
    k_conv<float><<<32,256, 4*580*4, stream>>>(encP2, spiral[3], enc_w[3], enc_b[3], encX3, 128, 128,7,  64,64,6, 576, 580, 4);
    k_pool4<<<4,256,0,stream>>>(encX3, dcol[3], dval[3], encP3, 1024, 31,5, 31,5, 128);
    k_enclat<<<64,256,0,stream>>>(encP3, enc_lat_w, enc_lat_b, pemb);

    // ---- decoder (XCD t-swizzled, all-bf16, pipelined convs) ----
    k_declin4<<<dim3(4,64),256,0,stream>>>(aemb, pemb, dec_lin_w, dec_lin_b, Pb);           // ->[64][32][128] bf16

    k_poolb<<<512,256,0,stream>>>(Pb, ucol[3], uval[3], Qb, 15,4, 127, 5,7, 3, 2048);        // ->[64][128][128]
    k_conv_p<1152,7,128,1,bf16><<<256,256,0,stream>>>(Qb, spiral[3], wt0, dec_b[0], Pb, 7, 2, 2);   // ->[64][128][128]

    k_poolb<<<2048,256,0,stream>>>(Pb, ucol[2], uval[2], Qb, 15,4, 511, 7,7, 5, 8192);       // ->[64][512][128]
    k_conv_p<1152,7,64,2,bf16><<<256,256,0,stream>>>(Qb, spiral[2], wt1, dec_b[1], Pb, 9, 2, 1);    // ->[64][512][64]

    k_poolb<<<4096,256,0,stream>>>(Pb, ucol[1], uval[1], Qb, 7,3, 2047, 9,6, 6, 16384);      // ->[64][2048][64]
    k_conv_p<576,6,64,2,bf16><<<1024,256,0,stream>>>(Qb, spiral[1], wt2, dec_b[2], Pb, 11, 4, 1);   // ->[64][2048][64]

    k_poolb<<<16384,256,0,stream>>>(Pb, ucol[0], uval[0], Qb, 7,3, 8191, 11,6, 8, 65536);    // ->[64][8192][64]
    k_conv_p<576,6,32,2,bf16><<<2048,256,0,stream>>>(Qb, spiral[0], wt3, dec_b[3], Pb, 13, 5, 0);   // ->[64][8192][32]

    k_outmfma<<<2048,256,0,stream>>>(Pb, spiral[0], wt4, dec_out_b, actor, (float*)d_out);
}

// Round 14
// 435.477 us; speedup vs baseline: 1.4089x; 1.0622x over previous
//
#include <hip/hip_runtime.h>
#include <hip/hip_bf16.h>

typedef __hip_bfloat16 bf16;
typedef __attribute__((ext_vector_type(8))) short short8v;
typedef __attribute__((ext_vector_type(16))) float f32x16;

__device__ __forceinline__ float tof(float v){ return v; }
__device__ __forceinline__ float tof(bf16 v){ return __bfloat162float(v); }
__device__ __forceinline__ void sto(float* p, float v){ *p = v; }
__device__ __forceinline__ void sto(bf16* p, float v){ *p = __float2bfloat16(v); }
__device__ __forceinline__ short f2bs(float f){ bf16 h = __float2bfloat16(f); return *(short*)&h; }
__device__ __forceinline__ float bsu2f(short s){
    return __uint_as_float(((unsigned)(unsigned short)s) << 16);
}

__device__ __forceinline__ void sto4(float* p, float4 v){ *(float4*)p = v; }
__device__ __forceinline__ void sto4(bf16* p, float4 v){
    short4 s; s.x=f2bs(v.x); s.y=f2bs(v.y); s.z=f2bs(v.z); s.w=f2bs(v.w);
    *(short4*)p = s;
}

// XCD-aware swizzle for 64-frame (t) problems: grid = 64 << bs blocks.
__device__ __forceinline__ void swz_t(int b, int bs, int& t, int& rem){
    int x = b & 7, k = b >> 3;
    t = x*8 + (k >> bs);
    rem = k & ((1 << bs) - 1);
}

// ---------- fused prep: 4 decoder transposes + outconv padded transpose
// + audio embedding (block-per-t, 4x64 LDS reduce) ----------
__global__ __launch_bounds__(256) void k_prep(
    const float* __restrict__ w0, const float* __restrict__ w1,
    const float* __restrict__ w2, const float* __restrict__ w3,
    const float* __restrict__ w4,
    short* __restrict__ wt0, short* __restrict__ wt1,
    short* __restrict__ wt2, short* __restrict__ wt3,
    short* __restrict__ wt4,
    const float* __restrict__ hs, const float* __restrict__ aw,
    const float* __restrict__ ab, float* __restrict__ aemb)
{
    __shared__ float red[4][64];
    int b = blockIdx.x, tid = threadIdx.x;
    if (b < 1080){
        const float* w; short* wt; int K, nsh, i;
        if      (b < 576) { w = w0; wt = wt0; K = 1152; nsh = 7; i = b*256 + tid; }
        else if (b < 864) { w = w1; wt = wt1; K = 1152; nsh = 6; i = (b-576)*256 + tid; }
        else if (b < 1008){ w = w2; wt = wt2; K = 576;  nsh = 6; i = (b-864)*256 + tid; }
        else              { w = w3; wt = wt3; K = 576;  nsh = 5; i = (b-1008)*256 + tid; }
        int k = i >> nsh, n = i & ((1 << nsh) - 1);
        wt[n*K + k] = f2bs(w[i]);
    } else if (b < 1116){
        int i = (b - 1080)*256 + tid;    // 0..9215
        int k = i >> 5, n = i & 31;
        wt4[n*288 + k] = (n < 3) ? f2bs(w4[k*3 + n]) : (short)0;
    } else {
        int t = b - 1116;                // 0..63
        int kg = tid >> 6, l = tid & 63;
        const float* h = hs + t*768;
        float acc = 0.f;
        int k0 = kg*192;
        #pragma unroll 8
        for (int k = k0; k < k0 + 192; k++) acc += h[k] * aw[k*64 + l];
        red[kg][l] = acc;
        __syncthreads();
        if (kg == 0)
            aemb[t*64 + l] = red[0][l] + red[1][l] + red[2][l] + red[3][l] + ab[l];
    }
}

// ---------- enc_lat ----------
__global__ __launch_bounds__(256) void k_enclat(const float* __restrict__ flat,
    const float* __restrict__ w, const float* __restrict__ b, float* __restrict__ out)
{
    __shared__ float red[256];
    int l = blockIdx.x, tid = threadIdx.x;
    float acc = 0.f;
    for (int k = tid; k < 4096; k += 256) acc += flat[k] * w[k*64 + l];
    red[tid] = acc; __syncthreads();
    for (int s = 128; s > 0; s >>= 1){ if (tid < s) red[tid] += red[tid+s]; __syncthreads(); }
    if (tid == 0) out[l] = red[0] + b[l];
}

// ---------- dec_lin fused with latent concat; bf16 out [t][32][128] ----------
__global__ __launch_bounds__(256) void k_declin4(const float* __restrict__ ae,
    const float* __restrict__ pe, const float* __restrict__ w, const float* __restrict__ b,
    bf16* __restrict__ out)
{
    int n4 = blockIdx.x*256 + threadIdx.x;   // 0..1023
    int t = blockIdx.y;
    float4 acc = *(const float4*)&b[n4*4];
    const float* a = ae + t*64;
    #pragma unroll 4
    for (int k = 0; k < 64; k++){
        float av = a[k];
        float4 wv = *(const float4*)&w[(size_t)k*4096 + n4*4];
        acc.x += av*wv.x; acc.y += av*wv.y; acc.z += av*wv.z; acc.w += av*wv.w;
    }
    #pragma unroll 4
    for (int k = 0; k < 64; k++){
        float pv = pe[k];
        float4 wv = *(const float4*)&w[(size_t)(64+k)*4096 + n4*4];
        acc.x += pv*wv.x; acc.y += pv*wv.y; acc.z += pv*wv.z; acc.w += pv*wv.w;
    }
    sto4(&out[(size_t)t*4096 + n4*4], acc);
}

// ---------- encoder 3-tap pool, f32, 4 ch/thread ----------
__global__ __launch_bounds__(256) void k_pool4(const float* __restrict__ xin,
    const int* __restrict__ col, const float* __restrict__ val, float* __restrict__ out,
    int total4, int c4mask, int cs, int vomask, int vos, int Vi)
{
    int i = blockIdx.x*256 + threadIdx.x;
    if (i >= total4) return;
    int c4 = i & c4mask;
    int rv = i >> cs;
    int r  = rv & vomask;
    int t  = rv >> vos;
    int C  = (c4mask + 1) << 2;
    const float* xt = xin + (size_t)t * Vi * C;
    int r3 = 3*r;
    int j0 = col[r3], j1 = col[r3+1], j2 = col[r3+2];
    float v0 = val[r3], v1 = val[r3+1], v2 = val[r3+2];
    int c = c4 << 2;
    float4 a = *(const float4*)&xt[(size_t)j0*C + c];
    float4 b = *(const float4*)&xt[(size_t)j1*C + c];
    float4 d = *(const float4*)&xt[(size_t)j2*C + c];
    float4 o;
    o.x = v0*a.x + v1*b.x + v2*d.x;
    o.y = v0*a.y + v1*b.y + v2*d.y;
    o.z = v0*a.z + v1*b.z + v2*d.z;
    o.w = v0*a.w + v1*b.w + v2*d.w;
    sto4(&out[(size_t)i << 2], o);
}

// ---------- decoder 3-tap pool, bf16 in/out, 8 ch/thread, t-swizzled ----------
__global__ __launch_bounds__(256) void k_poolb(const bf16* __restrict__ xin,
    const int* __restrict__ col, const float* __restrict__ val, bf16* __restrict__ out,
    int c8mask, int cs, int vom, int vshin, int cshift, int bs, int ept8)
{
    int t, rem; swz_t(blockIdx.x, bs, t, rem);
    int il = rem*256 + threadIdx.x;
    int c8 = il & c8mask;
    int r  = (il >> cs) & vom;
    size_t i = (size_t)t * ept8 + il;
    const bf16* xt = xin + ((size_t)t << (vshin + cshift));
    int r3 = 3*r;
    int j0 = col[r3], j1 = col[r3+1], j2 = col[r3+2];
    float v0 = val[r3], v1 = val[r3+1], v2 = val[r3+2];
    int c = c8 << 3;
    short8v a = *(const short8v*)&xt[((size_t)j0 << cshift) + c];
    short8v b = *(const short8v*)&xt[((size_t)j1 << cshift) + c];
    short8v d = *(const short8v*)&xt[((size_t)j2 << cshift) + c];
    short8v o;
    #pragma unroll
    for (int q = 0; q < 8; q++)
        o[q] = f2bs(v0*bsu2f(a[q]) + v1*bsu2f(b[q]) + v2*bsu2f(d[q]));
    *(short8v*)&out[i << 3] = o;
}

// ---------- deep-pipelined MFMA(32x32x16) spiral conv + ELU ----------
// 2-deep register prefetch + LDS double buffer: one barrier per K-chunk,
// loads for chunk ch+2 issued at iter-ch start (in flight ~2 compute phases).
// MT=128 rows/block. A frag: m=lane&31, k=half*8+j; B frag: n=lane&31.
// C/D: col=lane&31, row=(reg&3)+8*(reg>>2)+4*half  [verified m74/m101, r8-13]
template<int KTOT, int CSHIFT, int NTOT, typename TOUT>
__global__ __launch_bounds__(256) void k_conv_p2(
    const bf16* __restrict__ xin, const int* __restrict__ spiral,
    const short* __restrict__ wt, const float* __restrict__ bias, TOUT* __restrict__ out,
    int vshift, int bs, int nbshift)
{
    constexpr int NCH  = KTOT >> 6;
    constexpr int CSUB = CSHIFT - 6;
    __shared__ short lds_a[2*128*72];
    __shared__ short lds_b[2*32*72];
    const int tid = threadIdx.x;
    const int lane = tid & 63;
    const int wv = tid >> 6;
    const int col = lane & 31;
    const int half = lane >> 5;

    int t, rem; swz_t(blockIdx.x, bs, t, rem);
    const int nb = rem & ((1 << nbshift) - 1);
    const int vt = rem >> nbshift;
    const int mbase = vt*128;
    const size_t xslab = (size_t)t << (vshift + CSHIFT);

    const int am = tid >> 3;             // 0..31
    const int ak = (tid & 7) << 3;
    const int bn = tid >> 3;
    const int bk = (tid & 7) << 3;

    short8v pa[2][4];
    short8v pb[2];

    auto issue = [&](int ch, int st){
        int s = ch >> CSUB;
        int coff = ((ch & ((1 << CSUB) - 1)) << 6) + ak;
        #pragma unroll
        for (int u = 0; u < 4; u++){
            int j = spiral[(mbase + am + u*32)*9 + s];
            pa[st][u] = *(const short8v*)&xin[xslab + ((size_t)j << CSHIFT) + coff];
        }
        pb[st] = *(const short8v*)&wt[(size_t)(nb*32 + bn)*KTOT + (ch << 6) + bk];
    };
    auto commit = [&](int ch, int st){
        short* la = lds_a + (ch & 1)*(128*72);
        short* lb = lds_b + (ch & 1)*(32*72);
        #pragma unroll
        for (int u = 0; u < 4; u++)
            *(short8v*)&la[(am + u*32)*72 + ak] = pa[st][u];
        *(short8v*)&lb[bn*72 + bk] = pb[st];
    };

    f32x16 acc;
    {
        float bv = bias[nb*32 + col];
        #pragma unroll
        for (int r = 0; r < 16; r++) acc[r] = bv;
    }

    issue(0, 0);
    if (NCH > 1) issue(1, 1);
    commit(0, 0);
    __syncthreads();
    for (int ch = 0; ch < NCH; ch++){
        if (ch + 2 < NCH) issue(ch + 2, ch & 1);   // deepest in-flight window
        const short* la = lds_a + (ch & 1)*(128*72);
        const short* lb = lds_b + (ch & 1)*(32*72);
        #pragma unroll
        for (int ks = 0; ks < 4; ks++){
            short8v b = *(const short8v*)&lb[col*72 + ks*16 + half*8];
            short8v a = *(const short8v*)&la[(wv*32 + col)*72 + ks*16 + half*8];
            acc = __builtin_amdgcn_mfma_f32_32x32x16_bf16(a, b, acc, 0, 0, 0);
        }
        if (ch + 1 < NCH) commit(ch + 1, (ch + 1) & 1);  // writes OTHER buffer
        __syncthreads();                                 // single barrier/chunk
    }
    size_t mb = ((size_t)t << vshift) + mbase + wv*32;
    #pragma unroll
    for (int r = 0; r < 16; r++){
        int row = (r & 3) + 8*(r >> 2) + 4*half;
        float vv = acc[r];
        vv = vv > 0.f ? vv : __expf(vv) - 1.f;
        sto(&out[(mb + row)*NTOT + nb*32 + col], vv);
    }
}

// ---------- final conv as pipelined MFMA GEMM (N=3 padded to 32) + actor ----------
__global__ __launch_bounds__(256) void k_outmfma(
    const bf16* __restrict__ xin, const int* __restrict__ spiral,
    const short* __restrict__ wt, const float* __restrict__ bias,
    const float* __restrict__ actor, float* __restrict__ out)
{
    __shared__ short lds_a[256*36];
    __shared__ short lds_b[32*36];
    const int tid = threadIdx.x;
    const int lane = tid & 63;
    const int wv = tid >> 6;
    const int col = lane & 31;
    const int half = lane >> 5;

    int t, rem; swz_t(blockIdx.x, 5, t, rem);     // grid = 2048 = 64<<5
    const int mbase = rem*256;
    const size_t xslab = (size_t)t << 18;         // 8192 rows * 32 ch

    short8v pa[4];
    short8v pb;
    const int am = tid >> 2;          // 0..63
    const int ak = (tid & 3) << 3;    // short offset in 32-short row

    auto issue = [&](int s){
        #pragma unroll
        for (int u = 0; u < 4; u++){
            int j = spiral[(mbase + am + u*64)*9 + s];
            pa[u] = *(const short8v*)&xin[xslab + ((size_t)j << 5) + ak];
        }
        if (tid < 128)
            pb = *(const short8v*)&wt[am*288 + s*32 + ak];
    };
    auto commit = [&](){
        #pragma unroll
        for (int u = 0; u < 4; u++)
            *(short8v*)&lds_a[(am + u*64)*36 + ak] = pa[u];
        if (tid < 128)
            *(short8v*)&lds_b[am*36 + ak] = pb;
    };

    f32x16 acc[2];
    {
        float bv = (col < 3) ? bias[col] : 0.f;
        #pragma unroll
        for (int h = 0; h < 2; h++)
            #pragma unroll
            for (int r = 0; r < 16; r++) acc[h][r] = bv;
    }

    issue(0); commit(); __syncthreads();
    for (int s = 0; s < 9; s++){
        if (s + 1 < 9) issue(s + 1);
        #pragma unroll
        for (int ks = 0; ks < 2; ks++){
            short8v b = *(short8v*)&lds_b[col*36 + ks*16 + half*8];
            #pragma unroll
            for (int h = 0; h < 2; h++){
                short8v a = *(short8v*)&lds_a[(h*128 + wv*32 + col)*36 + ks*16 + half*8];
                acc[h] = __builtin_amdgcn_mfma_f32_32x32x16_bf16(a, b, acc[h], 0, 0, 0);
            }
        }
        __syncthreads();
        if (s + 1 < 9){ commit(); __syncthreads(); }
    }
    if (col < 3){
        #pragma unroll
        for (int h = 0; h < 2; h++){
            int rowb = mbase + h*128 + wv*32;
            #pragma unroll
            for (int r = 0; r < 16; r++){
                int row = rowb + (r & 3) + 8*(r >> 2) + 4*half;
                out[(((size_t)t << 13) + row)*3 + col] = acc[h][r] + actor[row*3 + col];
            }
        }
    }
}

// ---------- VALU spiral conv (encoder; tiny) ----------
template<typename TIN>
__global__ __launch_bounds__(256) void k_conv(const TIN* __restrict__ xin,
    const int* __restrict__ spiral, const float* __restrict__ w, const float* __restrict__ bias,
    float* __restrict__ out, int TV, int V, int vshift, int C, int O2, int o2shift,
    int K, int KP, int MT)
{
    extern __shared__ float lds[];
    const int S = 9;
    int tid = threadIdx.x;
    int O = O2 << 1;
    int gmbase = blockIdx.x * MT;

    int total = MT * K;
    for (int e = tid; e < total; e += 256){
        int m = e / K, k = e - m*K;
        int gm = gmbase + m;
        if (gm < TV){
            int t = gm >> vshift, v = gm & (V-1);
            int s = k / C, c = k - s*C;
            int jj = spiral[v*S + s];
            lds[m*KP + k] = tof(xin[((size_t)t*V + jj)*C + c]);
        }
    }
    __syncthreads();

    int m = tid >> o2shift;
    int o = tid & (O2 - 1);
    int gm = gmbase + m;
    if (gm >= TV) return;
    const float* g  = lds + m*KP;
    const float* wp = w + 2*o;
    float acc0 = bias[2*o];
    float acc1 = bias[2*o+1];
    int K4 = K & ~3;
    for (int k = 0; k < K4; k += 4){
        float4 g4 = *(const float4*)(g + k);
        float2 w0 = *(const float2*)(wp + (size_t)k    *O);
        float2 w1 = *(const float2*)(wp + (size_t)(k+1)*O);
        float2 w2 = *(const float2*)(wp + (size_t)(k+2)*O);
        float2 w3 = *(const float2*)(wp + (size_t)(k+3)*O);
        acc0 += g4.x*w0.x + g4.y*w1.x + g4.z*w2.x + g4.w*w3.x;
        acc1 += g4.x*w0.y + g4.y*w1.y + g4.z*w2.y + g4.w*w3.y;
    }
    for (int k = K4; k < K; k++){
        float gv = g[k];
        acc0 += gv * wp[(size_t)k*O];
        acc1 += gv * wp[(size_t)k*O + 1];
    }
    acc0 = acc0 > 0.f ? acc0 : __expf(acc0) - 1.f;
    acc1 = acc1 > 0.f ? acc1 : __expf(acc1) - 1.f;
    float2 r; r.x = acc0; r.y = acc1;
    *(float2*)(out + (size_t)gm*O + 2*o) = r;
}

extern "C" void kernel_launch(void* const* d_in, const int* in_sizes, int n_in,
                              void* d_out, int out_size, void* d_ws, size_t ws_size,
                              hipStream_t stream)
{
    (void)n_in; (void)out_size; (void)ws_size;
    const float* hs        = (const float*)d_in[0];
    const float* actor     = (const float*)d_in[1];
    const float* audio_w   = (const float*)d_in[2];
    const float* audio_b   = (const float*)d_in[3];
    const float* enc_w[4]  = {(const float*)d_in[4],(const float*)d_in[6],(const float*)d_in[8],(const float*)d_in[10]};
    const float* enc_b[4]  = {(const float*)d_in[5],(const float*)d_in[7],(const float*)d_in[9],(const float*)d_in[11]};
    const float* enc_lat_w = (const float*)d_in[12];
    const float* enc_lat_b = (const float*)d_in[13];
    const float* dec_lin_w = (const float*)d_in[14];
    const float* dec_lin_b = (const float*)d_in[15];
    const float* dec_w[4]  = {(const float*)d_in[16],(const float*)d_in[18],(const float*)d_in[20],(const float*)d_in[22]};
    const float* dec_b[4]  = {(const float*)d_in[17],(const float*)d_in[19],(const float*)d_in[21],(const float*)d_in[23]};
    const float* dec_out_w = (const float*)d_in[24];
    const float* dec_out_b = (const float*)d_in[25];
    const int*   spiral[4] = {(const int*)d_in[26],(const int*)d_in[27],(const int*)d_in[28],(const int*)d_in[29]};

    const int* dcol[4]; const float* dval[4]; const int* ucol[4]; const float* uval[4];
    bool interleaved = (in_sizes[33] == 3*8192);
    for (int i = 0; i < 4; i++){
        if (interleaved){
            int b = 30 + 6*i;
            dcol[i] = (const int*)d_in[b+1]; dval[i] = (const float*)d_in[b+2];
            ucol[i] = (const int*)d_in[b+4]; uval[i] = (const float*)d_in[b+5];
        } else {
            dcol[i] = (const int*)d_in[31+3*i]; dval[i] = (const float*)d_in[32+3*i];
            ucol[i] = (const int*)d_in[43+3*i]; uval[i] = (const float*)d_in[44+3*i];
        }
    }

    // ---- workspace ----
    char* ws = (char*)d_ws;
    size_t off = 0;
    auto alloc = [&](size_t bytes)->char* {
        char* p = ws + off; off += (bytes + 255) & ~(size_t)255; return p;
    };
    float* encX0 = (float*)alloc((size_t)262144*4);
    float* encP0 = (float*)alloc((size_t)65536*4);
    float* encX1 = (float*)alloc((size_t)131072*4);
    float* encP1 = (float*)alloc((size_t)32768*4);
    float* encX2 = (float*)alloc((size_t)32768*4);
    float* encP2 = (float*)alloc((size_t)8192*4);
    float* encX3 = (float*)alloc((size_t)16384*4);
    float* encP3 = (float*)alloc((size_t)4096*4);
    float* aemb  = (float*)alloc((size_t)4096*4);
    float* pemb  = (float*)alloc((size_t)64*4);
    short* wt0   = (short*)alloc((size_t)147456*2);   // dec0 [128][1152]
    short* wt1   = (short*)alloc((size_t)73728*2);    // dec1 [64][1152]
    short* wt2   = (short*)alloc((size_t)36864*2);    // dec2 [64][576]
    short* wt3   = (short*)alloc((size_t)18432*2);    // dec3 [32][576]
    short* wt4   = (short*)alloc((size_t)9216*2);     // out  [32pad][288]
    bf16*  Pb    = (bf16*)alloc((size_t)36*1048576);  // conv/declin outputs
    bf16*  Qb    = (bf16*)alloc((size_t)68*1048576);  // pool outputs

    // ---- prep (fused; 1080 transposes + 36 wt4 + 64 audio) ----
    k_prep<<<1180,256,0,stream>>>(dec_w[0], dec_w[1], dec_w[2], dec_w[3], dec_out_w,
                                  wt0, wt1, wt2, wt3, wt4, hs, audio_w, audio_b, aemb);

    // ---- encoder (VALU; tiny, B=1) ----
    k_conv<float><<<512,256, 16*28*4, stream>>>(actor, spiral[0], enc_w[0], enc_b[0], encX0, 8192, 8192,13,   3,16,4,  27,  28,16);
    k_pool4<<<64,256,0,stream>>>(encX0, dcol[0], dval[0], encP0, 16384, 7,3, 2047,11, 8192);
    k_conv<float><<<256,256, 8*292*4, stream>>>(encP0, spiral[1], enc_w[1], enc_b[1], encX1, 2048, 2048,11,  32,32,5, 288, 292, 8);
    k_pool4<<<32,256,0,stream>>>(encX1, dcol[1], dval[1], encP1, 8192, 15,4, 511,9, 2048);
    k_conv<float><<<64,256, 8*580*4, stream>>>(encP1, spiral[2], enc_w[2], enc_b[2], encX2, 512, 512,9,  64,32,5, 576, 580, 8);
    k_pool4<<<8,256,0,stream>>>(encX2, dcol[2], dval[2], encP2, 2048, 15,4, 127,7, 512);
    k_conv<float><<<32,256, 4*580*4, stream>>>(encP2, spiral[3], enc_w[3], enc_b[3], encX3, 128, 128,7,  64,64,6, 576, 580, 4);
    k_pool4<<<4,256,0,stream>>>(encX3, dcol[3], dval[3], encP3, 1024, 31,5, 31,5, 128);
    k_enclat<<<64,256,0,stream>>>(encP3, enc_lat_w, enc_lat_b, pemb);

    // ---- decoder (XCD t-swizzled, all-bf16, deep-pipelined convs) ----
    k_declin4<<<dim3(4,64),256,0,stream>>>(aemb, pemb, dec_lin_w, dec_lin_b, Pb);           // ->[64][32][128] bf16

    k_poolb<<<512,256,0,stream>>>(Pb, ucol[3], uval[3], Qb, 15,4, 127, 5,7, 3, 2048);        // ->[64][128][128]
    k_conv_p2<1152,7,128,bf16><<<256,256,0,stream>>>(Qb, spiral[3], wt0, dec_b[0], Pb, 7, 2, 2);   // ->[64][128][128]

    k_poolb<<<2048,256,0,stream>>>(Pb, ucol[2], uval[2], Qb, 15,4, 511, 7,7, 5, 8192);       // ->[64][512][128]
    k_conv_p2<1152,7,64,bf16><<<512,256,0,stream>>>(Qb, spiral[2], wt1, dec_b[1], Pb, 9, 3, 1);    // ->[64][512][64]

    k_poolb<<<4096,256,0,stream>>>(Pb, ucol[1], uval[1], Qb, 7,3, 2047, 9,6, 6, 16384);      // ->[64][2048][64]
    k_conv_p2<576,6,64,bf16><<<2048,256,0,stream>>>(Qb, spiral[1], wt2, dec_b[2], Pb, 11, 5, 1);   // ->[64][2048][64]

    k_poolb<<<16384,256,0,stream>>>(Pb, ucol[0], uval[0], Qb, 7,3, 8191, 11,6, 8, 65536);    // ->[64][8192][64]
    k_conv_p2<576,6,32,bf16><<<4096,256,0,stream>>>(Qb, spiral[0], wt3, dec_b[3], Pb, 13, 6, 0);   // ->[64][8192][32]

    k_outmfma<<<2048,256,0,stream>>>(Pb, spiral[0], wt4, dec_out_b, actor, (float*)d_out);
}